// Round 2
// baseline (1036.170 us; speedup 1.0000x reference)
//
#include <hip/hip_runtime.h>
#include <stdint.h>

#define NPTS   4096
#define NPOINT 1024
#define NSAMP  32
#define NROWS  262144   // B*NPOINT*NSAMP
#define RAD2   0.04f

typedef float v2f __attribute__((ext_vector_type(2)));
typedef __attribute__((ext_vector_type(8))) short bf16x8;
typedef __attribute__((ext_vector_type(4))) float f32x4;

// bf16 round-to-nearest-even
__device__ __forceinline__ unsigned short f2bf(float x) {
    unsigned u = __float_as_uint(x);
    return (unsigned short)((u + 0x7FFFu + ((u >> 16) & 1u)) >> 16);
}
__device__ __forceinline__ unsigned pack2bf(float a, float b) {
    return (unsigned)f2bf(a) | ((unsigned)f2bf(b) << 16);
}

// fused-DPP max helper (single-use feed -> v_max_f32_dpp)
#define DPPMAX(v, C)                                                           \
    fmaxf(__int_as_float(__builtin_amdgcn_update_dpp(                          \
              0, __float_as_int(v), C, 0xf, 0xf, true)),                       \
          (v))

// ---------------------------------------------------------------------------
// FPS: R16 — back to 256t/1-wave-per-SIMD (512t replicated the per-wave tail
// and regressed: D=444cy, T=285cy, stall=646cy from R14/R15 VALUBusy algebra).
// New: coords-in-key. The local argmax tracks the candidate's (x,y,z) (exact
// float copies -> bit-identical selection); the winning lane writes
// key+float4(coords) to LDS; post-barrier the coords ride the u64 compare
// tree. This fuses the two dependent LDS round trips (keys -> pxyz[farthest])
// into one and removes pxyz (64KB LDS) entirely.
// ---------------------------------------------------------------------------
__global__ __launch_bounds__(256) void fps_kernel(const float* __restrict__ xyz,
                                                  float* __restrict__ outx)
{
    __shared__ __align__(16) float4 orec[NPOINT];
    __shared__ __align__(16) unsigned long long wkey[2][4];
    __shared__ __align__(16) float4 wcrd[2][4];
    const int b = blockIdx.x, tid = threadIdx.x;
    const int lane = tid & 63;
    const int wid = tid >> 6;
    const float* base = xyz + b * 3 * NPTS;

    float Xs[16], Ys[16], Zs[16];
#pragma unroll
    for (int j = 0; j < 16; ++j) {
        const int n = j * 256 + tid;
        Xs[j] = base[n];
        Ys[j] = base[NPTS + n];
        Zs[j] = base[2 * NPTS + n];
    }
    v2f X2[8], Y2[8], Z2[8], D2[8];
#pragma unroll
    for (int j = 0; j < 8; ++j) {
        X2[j] = (v2f){Xs[2 * j], Xs[2 * j + 1]};
        Y2[j] = (v2f){Ys[2 * j], Ys[2 * j + 1]};
        Z2[j] = (v2f){Zs[2 * j], Zs[2 * j + 1]};
        D2[j] = (v2f){1e10f, 1e10f};
    }
    // initial centroid = point 0 (same values pxyz[0] held before)
    float cx = base[0], cy = base[NPTS], cz = base[2 * NPTS];

    for (int t = 0; t < NPOINT; ++t) {
        if (tid == 0) orec[t] = make_float4(cx, cy, cz, 0.0f);
        const v2f cxv = (v2f){cx, cx}, cyv = (v2f){cy, cy}, czv = (v2f){cz, cz};
        float bv = -1.0f; int bi = 0;
        float bx = 0.f, by = 0.f, bz = 0.f;
#pragma unroll
        for (int j = 0; j < 8; ++j) {
            v2f nd;
            {
#pragma clang fp contract(off)
                const v2f dx = X2[j] - cxv;
                const v2f dy = Y2[j] - cyv;
                const v2f dz = Z2[j] - czv;
                const v2f m0 = dx * dx;
                const v2f m1 = dy * dy;
                const v2f m2 = dz * dz;
                const v2f d = (m0 + m1) + m2;
                nd = __builtin_elementwise_min(D2[j], d);
            }
            D2[j] = nd;
            // ascending indices + strict > keep the first occurrence;
            // coords are exact copies of the candidate's floats
            if (nd.x > bv) { bv = nd.x; bi = j * 512 + tid;
                             bx = X2[j].x; by = Y2[j].x; bz = Z2[j].x; }
            if (nd.y > bv) { bv = nd.y; bi = j * 512 + 256 + tid;
                             bx = X2[j].y; by = Y2[j].y; bz = Z2[j].y; }
        }
        // value-first fused-DPP max
        float rv = bv;                       // bv >= 0 (bound_ctrl 0-fill safe)
        rv = DPPMAX(rv, 0x111);              // row_shr:1
        rv = DPPMAX(rv, 0x112);              // row_shr:2
        rv = DPPMAX(rv, 0x114);              // row_shr:4
        rv = DPPMAX(rv, 0x118);              // row_shr:8
        rv = DPPMAX(rv, 0x142);              // row_bcast:15
        rv = DPPMAX(rv, 0x143);              // row_bcast:31
        const unsigned wmax =
            (unsigned)__builtin_amdgcn_readlane(__float_as_int(rv), 63);
        // index resolution: ballot + scalar min over matching lanes,
        // tracking the winning LANE so it can write its own key+coords
        unsigned long long mask = __ballot(__float_as_uint(bv) == wmax);
        int bl = (int)__builtin_ctzll(mask);
        unsigned best = (unsigned)__builtin_amdgcn_readlane(bi, bl);
        mask &= mask - 1ull;
        while (mask) {
            const int l = (int)__builtin_ctzll(mask);
            const unsigned cand = (unsigned)__builtin_amdgcn_readlane(bi, l);
            if (cand < best) { best = cand; bl = l; }
            mask &= mask - 1ull;
        }
        if (lane == bl) {
            // this lane's bv == wmax and bi == best
            wkey[t & 1][wid] =
                ((unsigned long long)__float_as_uint(bv) << 32) |
                (unsigned)(~bi);
            wcrd[t & 1][wid] = make_float4(bx, by, bz, 0.0f);
        }
        __syncthreads();
        // cross-wave reduce: key compare tree with coords riding along
        const ulonglong2* wk = (const ulonglong2*)wkey[t & 1];
        const ulonglong2 ka = wk[0], kb = wk[1];
        const float4 c0 = wcrd[t & 1][0];
        const float4 c1 = wcrd[t & 1][1];
        const float4 c2 = wcrd[t & 1][2];
        const float4 c3 = wcrd[t & 1][3];
        const bool s0 = ka.y > ka.x;
        const unsigned long long k0 = s0 ? ka.y : ka.x;
        float px = s0 ? c1.x : c0.x;
        float py = s0 ? c1.y : c0.y;
        float pz = s0 ? c1.z : c0.z;
        const bool s1 = kb.y > kb.x;
        const unsigned long long k1 = s1 ? kb.y : kb.x;
        const float qx = s1 ? c3.x : c2.x;
        const float qy = s1 ? c3.y : c2.y;
        const float qz = s1 ? c3.z : c2.z;
        const bool s2 = k1 > k0;
        cx = s2 ? qx : px;
        cy = s2 ? qy : py;
        cz = s2 ? qz : pz;
    }
    __syncthreads();
    float* ox = outx + b * 3 * NPOINT;
    for (int i = tid; i < NPOINT; i += 256) {
        const float4 c = orec[i];
        ox[i]              = c.x;
        ox[NPOINT + i]     = c.y;
        ox[2 * NPOINT + i] = c.z;
    }
}

// ---------------------------------------------------------------------------
// Ball query + fused moments + packed-bf16 feature store. One wave per query:
// first 32 in-radius indices; lanes 0-31 gather their row's features once,
// accumulate m1[6]/M2[36], AND store the row's packed bf16 uint4 (exactly the
// LDS A-tile format) to featbuf -> mlp kernels never gather again.
// ---------------------------------------------------------------------------
__global__ __launch_bounds__(256) void ball_kernel(const float* __restrict__ xyz,
                                                   const float* __restrict__ pts,
                                                   const float* __restrict__ outx,
                                                   int* __restrict__ idxbuf,
                                                   float* __restrict__ mom,
                                                   uint4* __restrict__ featbuf)
{
    __shared__ float red[4][42];
    const int tid = threadIdx.x;
    const int w = blockIdx.x * 4 + (tid >> 6);
    const int lane = tid & 63, wid = tid >> 6;
    const int b = w >> 10, s = w & 1023;
    const float* base = xyz + b * 3 * NPTS;
    const float cx = outx[b * 3 * NPOINT + s];
    const float cy = outx[b * 3 * NPOINT + NPOINT + s];
    const float cz = outx[b * 3 * NPOINT + 2 * NPOINT + s];
    const float sumS = __fadd_rn(__fadd_rn(__fmul_rn(cx, cx), __fmul_rn(cy, cy)),
                                 __fmul_rn(cz, cz));
    int cnt = 0, first_n = -1;
    int* myidx = idxbuf + w * NSAMP;

    for (int chunk = 0; chunk < NPTS / 64 && cnt < NSAMP; ++chunk) {
        const int n = chunk * 64 + lane;
        float nx = base[n], ny = base[NPTS + n], nz = base[2 * NPTS + n];
        float sumN = __fadd_rn(__fadd_rn(__fmul_rn(nx, nx), __fmul_rn(ny, ny)),
                               __fmul_rn(nz, nz));
        float dot = __fadd_rn(__fadd_rn(__fmul_rn(cx, nx), __fmul_rn(cy, ny)),
                              __fmul_rn(cz, nz));
        float sq = __fsub_rn(__fadd_rn(sumS, sumN), __fmul_rn(2.0f, dot));
        bool keep = (sq <= RAD2);
        unsigned long long mask = __ballot(keep);
        if (first_n < 0 && mask) first_n = chunk * 64 + (int)__builtin_ctzll(mask);
        int pos = cnt + __popcll(mask & ((1ull << lane) - 1ull));
        if (keep && pos < NSAMP) myidx[pos] = n;
        cnt += __popcll(mask);
    }
    if (cnt < NSAMP) {
        if (lane >= cnt && lane < NSAMP) myidx[lane] = first_n;
    }

    // ---- fused moments + feature store for this wave's 32 rows ----
    float m[42];
#pragma unroll
    for (int i = 0; i < 42; ++i) m[i] = 0.f;
    if (lane < 32) {
        const int idx = myidx[lane];
        const float* pb = pts + b * 3 * NPTS;
        float f[6];
        f[0] = base[idx] - cx;
        f[1] = base[NPTS + idx] - cy;
        f[2] = base[2 * NPTS + idx] - cz;
        f[3] = pb[idx];
        f[4] = pb[NPTS + idx];
        f[5] = pb[2 * NPTS + idx];
        featbuf[w * NSAMP + lane] =
            make_uint4(pack2bf(f[0], f[1]), pack2bf(f[2], f[3]),
                       pack2bf(f[4], f[5]), 0u);
#pragma unroll
        for (int c = 0; c < 6; ++c) m[c] = f[c];
#pragma unroll
        for (int c = 0; c < 6; ++c)
#pragma unroll
            for (int d = 0; d < 6; ++d)
                m[6 + c * 6 + d] = f[c] * f[d];
    }
#pragma unroll
    for (int i = 0; i < 42; ++i) {
        float v = m[i];
        v += __shfl_xor(v, 1);  v += __shfl_xor(v, 2);  v += __shfl_xor(v, 4);
        v += __shfl_xor(v, 8);  v += __shfl_xor(v, 16); v += __shfl_xor(v, 32);
        m[i] = v;
    }
    if (lane == 0) {
#pragma unroll
        for (int i = 0; i < 42; ++i) red[wid][i] = m[i];
    }
    __syncthreads();
    if (tid < 42)
        atomicAdd(&mom[tid], red[0][tid] + red[1][tid] + red[2][tid] + red[3][tid]);
}

// bn0 from feature moments (biases cancel through BN shift; bilinear in W0)
__device__ __forceinline__ void compute_bn0(int o, const float* __restrict__ mom,
                                            const float* __restrict__ w0,
                                            const float* __restrict__ g,
                                            const float* __restrict__ be,
                                            float* __restrict__ sbn0)
{
    float w[6];
#pragma unroll
    for (int c = 0; c < 6; ++c) w[c] = w0[o * 6 + c];
    const float inv = 1.0f / (float)NROWS;
    float mean = 0.f;
#pragma unroll
    for (int c = 0; c < 6; ++c) mean = fmaf(w[c], mom[c], mean);
    mean *= inv;
    float ey2 = 0.f;
#pragma unroll
    for (int c = 0; c < 6; ++c) {
        float t = 0.f;
#pragma unroll
        for (int d = 0; d < 6; ++d) t = fmaf(w[d], mom[6 + c * 6 + d], t);
        ey2 = fmaf(w[c], t, ey2);
    }
    ey2 *= inv;
    const float var = ey2 - mean * mean;
    const float scale = g[o] * rsqrtf(var + 1e-5f);
    sbn0[o] = scale;
    sbn0[64 + o] = be[o] - mean * scale;
}

// ===========================================================================
// MFMA MLP kernels (R8-validated structure): 512 blocks x 512 rows (4 chunks
// of 128), weights staged once per block, stats in registers across chunks.
// A-tile rows loaded as ONE coalesced uint4 from featbuf (no gather).
// mfma_f32_16x16x32_bf16: A[m=lane&15][k=q*8+j], B[k=q*8+j][n=lane&15],
// D[row=q*4+r][col=lane&15]  (q = lane>>4).
// ===========================================================================
#define XP  72
#define WP  72
#define W0P 40

// ---- mlp1: feat -> L0 -> bn0(inline from moments) -> L1 -> stats1 -----------
__global__ __launch_bounds__(256, 2) void mlp1_kernel(
    const uint4* __restrict__ featbuf,
    const float* __restrict__ w0, const float* __restrict__ mom,
    const float* __restrict__ g0, const float* __restrict__ be0,
    const float* __restrict__ w1, float* __restrict__ stats)
{
    __shared__ __align__(16) unsigned short sw0[64 * W0P];
    __shared__ __align__(16) unsigned short sw1[64 * WP];
    __shared__ __align__(16) unsigned short xb[4][32 * XP];
    __shared__ float sbn0[128];
    __shared__ float red[4][128];
    const int tid = threadIdx.x, lane = tid & 63, wid = tid >> 6;

    for (int i = tid; i < 64 * W0P / 2; i += 256) ((unsigned*)sw0)[i] = 0;
    if (tid < 64) compute_bn0(tid, mom, w0, g0, be0, sbn0);
    __syncthreads();
    for (int i = tid; i < 192; i += 256) {
        const int o = i / 3, c = (i % 3) * 2;
        *(unsigned*)&sw0[o * W0P + c] = pack2bf(w0[o * 6 + c], w0[o * 6 + c + 1]);
    }
    for (int i = tid; i < 2048; i += 256) {
        const int o = i >> 5, k = (i & 31) * 2;
        *(unsigned*)&sw1[o * WP + k] = pack2bf(w1[o * 64 + k], w1[o * 64 + k + 1]);
    }

    const int mh = lane & 15, q = lane >> 4;
    unsigned short* X = xb[wid];
    const int rbase = blockIdx.x * 512 + wid * 32;
    float sA[4] = {0.f, 0.f, 0.f, 0.f}, qA[4] = {0.f, 0.f, 0.f, 0.f};

    for (int c = 0; c < 4; ++c) {
        __syncthreads();
        if (lane < 32) {
            const int r = rbase + c * 128 + lane;
            uint4* xq = (uint4*)&xb[wid][lane * XP];
            xq[0] = featbuf[r];
            xq[1] = make_uint4(0u, 0u, 0u, 0u);
            xq[2] = make_uint4(0u, 0u, 0u, 0u);
            xq[3] = make_uint4(0u, 0u, 0u, 0u);
        }
        __syncthreads();
        // L0
        f32x4 acc0[2][4] = {};
        {
            bf16x8 a[2], bw[4];
#pragma unroll
            for (int mt = 0; mt < 2; ++mt)
                a[mt] = *(const bf16x8*)&X[(mt * 16 + mh) * XP + q * 8];
#pragma unroll
            for (int nt = 0; nt < 4; ++nt)
                bw[nt] = *(const bf16x8*)&sw0[(nt * 16 + mh) * W0P + q * 8];
#pragma unroll
            for (int mt = 0; mt < 2; ++mt)
#pragma unroll
                for (int nt = 0; nt < 4; ++nt)
                    acc0[mt][nt] = __builtin_amdgcn_mfma_f32_16x16x32_bf16(
                        a[mt], bw[nt], acc0[mt][nt], 0, 0, 0);
        }
        __syncthreads();
#pragma unroll
        for (int nt = 0; nt < 4; ++nt) {
            const int ch = nt * 16 + mh;
            const float sc = sbn0[ch], sh = sbn0[64 + ch];
#pragma unroll
            for (int mt = 0; mt < 2; ++mt)
#pragma unroll
                for (int rr = 0; rr < 4; ++rr) {
                    const float v = fmaxf(fmaf(acc0[mt][nt][rr], sc, sh), 0.0f);
                    X[(mt * 16 + q * 4 + rr) * XP + ch] = f2bf(v);
                }
        }
        __syncthreads();
        // L1
        f32x4 acc1[2][4] = {};
#pragma unroll
        for (int ks = 0; ks < 2; ++ks) {
            bf16x8 a[2], bw[4];
#pragma unroll
            for (int mt = 0; mt < 2; ++mt)
                a[mt] = *(const bf16x8*)&X[(mt * 16 + mh) * XP + ks * 32 + q * 8];
#pragma unroll
            for (int nt = 0; nt < 4; ++nt)
                bw[nt] = *(const bf16x8*)&sw1[(nt * 16 + mh) * WP + ks * 32 + q * 8];
#pragma unroll
            for (int mt = 0; mt < 2; ++mt)
#pragma unroll
                for (int nt = 0; nt < 4; ++nt)
                    acc1[mt][nt] = __builtin_amdgcn_mfma_f32_16x16x32_bf16(
                        a[mt], bw[nt], acc1[mt][nt], 0, 0, 0);
        }
#pragma unroll
        for (int nt = 0; nt < 4; ++nt)
#pragma unroll
            for (int mt = 0; mt < 2; ++mt)
#pragma unroll
                for (int rr = 0; rr < 4; ++rr) {
                    const float v = acc1[mt][nt][rr];
                    sA[nt] += v;
                    qA[nt] = fmaf(v, v, qA[nt]);
                }
    }
#pragma unroll
    for (int nt = 0; nt < 4; ++nt) {
        float s = sA[nt], qq = qA[nt];
        s += __shfl_xor(s, 16); qq += __shfl_xor(qq, 16);
        s += __shfl_xor(s, 32); qq += __shfl_xor(qq, 32);
        if (q == 0) {
            red[wid][nt * 16 + mh] = s;
            red[wid][64 + nt * 16 + mh] = qq;
        }
    }
    __syncthreads();
    if (tid < 128)
        atomicAdd(&stats[tid],
                  red[0][tid] + red[1][tid] + red[2][tid] + red[3][tid]);
}

// ---- mlp2: feat -> L0 -> bn0 -> L1 -> bn1(inline) -> L2 -> stats2 + max -----
__global__ __launch_bounds__(256, 2) void mlp2_kernel(
    const uint4* __restrict__ featbuf,
    const float* __restrict__ w0, const float* __restrict__ mom,
    const float* __restrict__ g0, const float* __restrict__ be0,
    const float* __restrict__ w1, const float* __restrict__ stats1,
    const float* __restrict__ g1, const float* __restrict__ be1,
    const float* __restrict__ w2,
    float* __restrict__ stats, float* __restrict__ gmax)
{
    __shared__ __align__(16) unsigned short sw0[64 * W0P];
    __shared__ __align__(16) unsigned short sw1[64 * WP];
    __shared__ __align__(16) unsigned short sw2[128 * WP];
    __shared__ __align__(16) unsigned short xb[4][32 * XP];
    __shared__ float sbn0[128];
    __shared__ float sbn1[128];
    __shared__ float red[4][256];
    const int tid = threadIdx.x, lane = tid & 63, wid = tid >> 6;

    for (int i = tid; i < 64 * W0P / 2; i += 256) ((unsigned*)sw0)[i] = 0;
    if (tid < 64) {
        compute_bn0(tid, mom, w0, g0, be0, sbn0);
    } else if (tid < 128) {
        const int ch = tid - 64;
        const float inv = 1.0f / (float)NROWS;
        const float mean = stats1[ch] * inv;
        const float var = stats1[64 + ch] * inv - mean * mean;
        const float scale = g1[ch] * rsqrtf(var + 1e-5f);
        sbn1[ch] = scale;
        sbn1[64 + ch] = be1[ch] - mean * scale;
    }
    __syncthreads();
    for (int i = tid; i < 192; i += 256) {
        const int o = i / 3, c = (i % 3) * 2;
        *(unsigned*)&sw0[o * W0P + c] = pack2bf(w0[o * 6 + c], w0[o * 6 + c + 1]);
    }
    for (int i = tid; i < 2048; i += 256) {
        const int o = i >> 5, k = (i & 31) * 2;
        *(unsigned*)&sw1[o * WP + k] = pack2bf(w1[o * 64 + k], w1[o * 64 + k + 1]);
    }
    for (int i = tid; i < 4096; i += 256) {
        const int o = i >> 5, k = (i & 31) * 2;
        *(unsigned*)&sw2[o * WP + k] = pack2bf(w2[o * 64 + k], w2[o * 64 + k + 1]);
    }

    const int mh = lane & 15, q = lane >> 4;
    unsigned short* X = xb[wid];
    const int rbase = blockIdx.x * 512 + wid * 32;
    float sA[8], qA[8];
#pragma unroll
    for (int i = 0; i < 8; ++i) { sA[i] = 0.f; qA[i] = 0.f; }

    for (int c = 0; c < 4; ++c) {
        __syncthreads();
        if (lane < 32) {
            const int r = rbase + c * 128 + lane;
            uint4* xq = (uint4*)&xb[wid][lane * XP];
            xq[0] = featbuf[r];
            xq[1] = make_uint4(0u, 0u, 0u, 0u);
            xq[2] = make_uint4(0u, 0u, 0u, 0u);
            xq[3] = make_uint4(0u, 0u, 0u, 0u);
        }
        __syncthreads();
        // L0
        f32x4 acc0[2][4] = {};
        {
            bf16x8 a[2], bw[4];
#pragma unroll
            for (int mt = 0; mt < 2; ++mt)
                a[mt] = *(const bf16x8*)&X[(mt * 16 + mh) * XP + q * 8];
#pragma unroll
            for (int nt = 0; nt < 4; ++nt)
                bw[nt] = *(const bf16x8*)&sw0[(nt * 16 + mh) * W0P + q * 8];
#pragma unroll
            for (int mt = 0; mt < 2; ++mt)
#pragma unroll
                for (int nt = 0; nt < 4; ++nt)
                    acc0[mt][nt] = __builtin_amdgcn_mfma_f32_16x16x32_bf16(
                        a[mt], bw[nt], acc0[mt][nt], 0, 0, 0);
        }
        __syncthreads();
#pragma unroll
        for (int nt = 0; nt < 4; ++nt) {
            const int ch = nt * 16 + mh;
            const float sc = sbn0[ch], sh = sbn0[64 + ch];
#pragma unroll
            for (int mt = 0; mt < 2; ++mt)
#pragma unroll
                for (int rr = 0; rr < 4; ++rr) {
                    const float v = fmaxf(fmaf(acc0[mt][nt][rr], sc, sh), 0.0f);
                    X[(mt * 16 + q * 4 + rr) * XP + ch] = f2bf(v);
                }
        }
        __syncthreads();
        // L1
        f32x4 acc1[2][4] = {};
#pragma unroll
        for (int ks = 0; ks < 2; ++ks) {
            bf16x8 a[2], bw[4];
#pragma unroll
            for (int mt = 0; mt < 2; ++mt)
                a[mt] = *(const bf16x8*)&X[(mt * 16 + mh) * XP + ks * 32 + q * 8];
#pragma unroll
            for (int nt = 0; nt < 4; ++nt)
                bw[nt] = *(const bf16x8*)&sw1[(nt * 16 + mh) * WP + ks * 32 + q * 8];
#pragma unroll
            for (int mt = 0; mt < 2; ++mt)
#pragma unroll
                for (int nt = 0; nt < 4; ++nt)
                    acc1[mt][nt] = __builtin_amdgcn_mfma_f32_16x16x32_bf16(
                        a[mt], bw[nt], acc1[mt][nt], 0, 0, 0);
        }
        __syncthreads();
#pragma unroll
        for (int nt = 0; nt < 4; ++nt) {
            const int ch = nt * 16 + mh;
            const float sc = sbn1[ch], sh = sbn1[64 + ch];
#pragma unroll
            for (int mt = 0; mt < 2; ++mt)
#pragma unroll
                for (int rr = 0; rr < 4; ++rr) {
                    const float v = fmaxf(fmaf(acc1[mt][nt][rr], sc, sh), 0.0f);
                    X[(mt * 16 + q * 4 + rr) * XP + ch] = f2bf(v);
                }
        }
        __syncthreads();
        // L2 + stats accumulate + per-group (32-row) max
        const int g = blockIdx.x * 16 + c * 4 + wid;
        bf16x8 a2[2][2];
#pragma unroll
        for (int mt = 0; mt < 2; ++mt)
#pragma unroll
            for (int ks = 0; ks < 2; ++ks)
                a2[mt][ks] = *(const bf16x8*)&X[(mt * 16 + mh) * XP + ks * 32 + q * 8];
#pragma unroll
        for (int nt = 0; nt < 8; ++nt) {
            f32x4 acc[2] = {};
#pragma unroll
            for (int ks = 0; ks < 2; ++ks) {
                const bf16x8 bw = *(const bf16x8*)&sw2[(nt * 16 + mh) * WP + ks * 32 + q * 8];
#pragma unroll
                for (int mt = 0; mt < 2; ++mt)
                    acc[mt] = __builtin_amdgcn_mfma_f32_16x16x32_bf16(
                        a2[mt][ks], bw, acc[mt], 0, 0, 0);
            }
            float m = -3.0e38f;
#pragma unroll
            for (int mt = 0; mt < 2; ++mt)
#pragma unroll
                for (int rr = 0; rr < 4; ++rr) {
                    const float v = acc[mt][rr];
                    sA[nt] += v;
                    qA[nt] = fmaf(v, v, qA[nt]);
                    m = fmaxf(m, v);
                }
            m = fmaxf(m, __shfl_xor(m, 16));
            m = fmaxf(m, __shfl_xor(m, 32));
            if (q == 0) gmax[(nt * 16 + mh) * 8192 + g] = m;
        }
    }
#pragma unroll
    for (int nt = 0; nt < 8; ++nt) {
        float s = sA[nt], qq = qA[nt];
        s += __shfl_xor(s, 16); qq += __shfl_xor(qq, 16);
        s += __shfl_xor(s, 32); qq += __shfl_xor(qq, 32);
        if (q == 0) {
            red[wid][nt * 16 + mh] = s;
            red[wid][128 + nt * 16 + mh] = qq;
        }
    }
    __syncthreads();
    atomicAdd(&stats[tid],
              red[0][tid] + red[1][tid] + red[2][tid] + red[3][tid]);
}

// ---------------------------------------------------------------------------
// final: bn2 computed inline from stats2; out2[b,o,s] = relu(bn2(gmax))
// ---------------------------------------------------------------------------
__global__ __launch_bounds__(256) void final_kernel(const float* __restrict__ gmax,
                                                    const float* __restrict__ stats2,
                                                    const float* __restrict__ g2,
                                                    const float* __restrict__ be2,
                                                    float* __restrict__ out2)
{
    __shared__ float sbn[256];
    const int tid = threadIdx.x;
    if (tid < 128) {
        const float inv = 1.0f / (float)NROWS;
        const float mean = stats2[tid] * inv;
        const float var = stats2[128 + tid] * inv - mean * mean;
        const float scale = g2[tid] * rsqrtf(var + 1e-5f);
        sbn[tid] = scale;
        sbn[128 + tid] = be2[tid] - mean * scale;
    }
    __syncthreads();
    const int t = blockIdx.x * 256 + tid;
    const int s = t & 1023;
    const int o = (t >> 10) & 127;
    const int b = t >> 17;
    const int g = (b << 10) | s;
    float v = gmax[o * 8192 + g];
    v = fmaf(v, sbn[o], sbn[128 + o]);
    out2[t] = fmaxf(v, 0.0f);
}

// ---------------------------------------------------------------------------
extern "C" void kernel_launch(void* const* d_in, const int* in_sizes, int n_in,
                              void* d_out, int out_size, void* d_ws, size_t ws_size,
                              hipStream_t stream)
{
    const float* xyz = (const float*)d_in[0];
    const float* pts = (const float*)d_in[1];
    const float* w0  = (const float*)d_in[2];
    const float* g0  = (const float*)d_in[4];
    const float* be0 = (const float*)d_in[5];
    const float* w1  = (const float*)d_in[6];
    const float* g1  = (const float*)d_in[8];
    const float* be1 = (const float*)d_in[9];
    const float* w2  = (const float*)d_in[10];
    const float* g2  = (const float*)d_in[12];
    const float* be2 = (const float*)d_in[13];

    float* out_xyz = (float*)d_out;             // (B,3,1024)
    float* out2    = out_xyz + 8 * 3 * NPOINT;  // (B,128,1024)

    char* wsb = (char*)d_ws;
    int*   idxbuf  = (int*)(wsb + 32768);               // 262144 ints (1 MB)
    float* stats   = (float*)(wsb + 32768 + 1048576);   // 512 floats
    float* gmax    = stats + 1024;                      // 128*8192 floats (4 MB)
    uint4* featbuf = (uint4*)(gmax + 128 * 8192);       // 262144 uint4 (4 MB)

    float* mom    = stats;                              // 42 floats
    float* stats1 = stats + 128;
    float* stats2 = stats + 256;

    hipMemsetAsync(stats, 0, 512 * sizeof(float), stream);

    fps_kernel<<<8, 256, 0, stream>>>(xyz, out_xyz);
    ball_kernel<<<2048, 256, 0, stream>>>(xyz, pts, out_xyz, idxbuf, mom, featbuf);
    mlp1_kernel<<<512, 256, 0, stream>>>(featbuf, w0, mom, g0, be0, w1, stats1);
    mlp2_kernel<<<512, 256, 0, stream>>>(featbuf, w0, mom, g0, be0,
                                         w1, stats1, g1, be1,
                                         w2, stats2, gmax);
    final_kernel<<<4096, 256, 0, stream>>>(gmax, stats2, g2, be2, out2);
}

// Round 3
// 793.255 us; speedup vs baseline: 1.3062x; 1.3062x over previous
//
#include <hip/hip_runtime.h>
#include <stdint.h>

#define NPTS   4096
#define NPOINT 1024
#define NSAMP  32
#define NROWS  262144   // B*NPOINT*NSAMP
#define RAD2   0.04f

typedef float v2f __attribute__((ext_vector_type(2)));
typedef __attribute__((ext_vector_type(8))) short bf16x8;
typedef __attribute__((ext_vector_type(4))) float f32x4;

// bf16 round-to-nearest-even
__device__ __forceinline__ unsigned short f2bf(float x) {
    unsigned u = __float_as_uint(x);
    return (unsigned short)((u + 0x7FFFu + ((u >> 16) & 1u)) >> 16);
}
__device__ __forceinline__ unsigned pack2bf(float a, float b) {
    return (unsigned)f2bf(a) | ((unsigned)f2bf(b) << 16);
}

// fused-DPP max helper (single-use feed -> v_max_f32_dpp)
#define DPPMAX(v, C)                                                           \
    fmaxf(__int_as_float(__builtin_amdgcn_update_dpp(                          \
              0, __float_as_int(v), C, 0xf, 0xf, true)),                       \
          (v))

// ---------------------------------------------------------------------------
// FPS: frozen at R14 state (587us). 7 structural variants tried (5 prior
// session + R15 2-wave overlap [+45us: tail replicates per wave] + R16
// coords-in-key [+235us: VGPR 132->68, state spilled to AGPR shuttle]).
// DO NOT TOUCH: 132 VGPRs keeps the 64-reg point state resident.
// ---------------------------------------------------------------------------
__global__ __launch_bounds__(256) void fps_kernel(const float* __restrict__ xyz,
                                                  float* __restrict__ outx)
{
    __shared__ __align__(16) float4 pxyz[NPTS];
    __shared__ __align__(16) float4 orec[NPOINT];
    __shared__ __align__(16) unsigned long long wkey[2][4];
    const int b = blockIdx.x, tid = threadIdx.x;
    const int lane = tid & 63, wid = tid >> 6;
    const float* base = xyz + b * 3 * NPTS;

    float Xs[16], Ys[16], Zs[16];
#pragma unroll
    for (int j = 0; j < 16; ++j) {
        const int n = j * 256 + tid;
        Xs[j] = base[n];
        Ys[j] = base[NPTS + n];
        Zs[j] = base[2 * NPTS + n];
        pxyz[n] = make_float4(Xs[j], Ys[j], Zs[j], 0.0f);
    }
    v2f X2[8], Y2[8], Z2[8], D2[8];
#pragma unroll
    for (int j = 0; j < 8; ++j) {
        X2[j] = (v2f){Xs[2 * j], Xs[2 * j + 1]};
        Y2[j] = (v2f){Ys[2 * j], Ys[2 * j + 1]};
        Z2[j] = (v2f){Zs[2 * j], Zs[2 * j + 1]};
        D2[j] = (v2f){1e10f, 1e10f};
    }
    __syncthreads();
    float4 c4 = pxyz[0];
    float cx = c4.x, cy = c4.y, cz = c4.z;

    for (int t = 0; t < NPOINT; ++t) {
        if (tid == 0) orec[t] = make_float4(cx, cy, cz, 0.0f);
        const v2f cxv = (v2f){cx, cx}, cyv = (v2f){cy, cy}, czv = (v2f){cz, cz};
        float bv = -1.0f; int bi = 0;
#pragma unroll
        for (int j = 0; j < 8; ++j) {
            v2f nd;
            {
#pragma clang fp contract(off)
                const v2f dx = X2[j] - cxv;
                const v2f dy = Y2[j] - cyv;
                const v2f dz = Z2[j] - czv;
                const v2f m0 = dx * dx;
                const v2f m1 = dy * dy;
                const v2f m2 = dz * dz;
                const v2f d = (m0 + m1) + m2;
                nd = __builtin_elementwise_min(D2[j], d);
            }
            D2[j] = nd;
            // ascending indices + strict > keep the first occurrence
            if (nd.x > bv) { bv = nd.x; bi = j * 512 + tid; }
            if (nd.y > bv) { bv = nd.y; bi = j * 512 + 256 + tid; }
        }
        // value-first fused-DPP max
        float rv = bv;                       // bv >= 0 (bound_ctrl 0-fill safe)
        rv = DPPMAX(rv, 0x111);              // row_shr:1
        rv = DPPMAX(rv, 0x112);              // row_shr:2
        rv = DPPMAX(rv, 0x114);              // row_shr:4
        rv = DPPMAX(rv, 0x118);              // row_shr:8
        rv = DPPMAX(rv, 0x142);              // row_bcast:15
        rv = DPPMAX(rv, 0x143);              // row_bcast:31
        const unsigned wmax =
            (unsigned)__builtin_amdgcn_readlane(__float_as_int(rv), 63);
        // index resolution: ballot + scalar min over matching lanes
        unsigned long long mask = __ballot(__float_as_uint(bv) == wmax);
        unsigned best =
            (unsigned)__builtin_amdgcn_readlane(bi, (int)__builtin_ctzll(mask));
        mask &= mask - 1ull;
        while (mask) {
            const unsigned cand = (unsigned)__builtin_amdgcn_readlane(
                bi, (int)__builtin_ctzll(mask));
            best = cand < best ? cand : best;
            mask &= mask - 1ull;
        }
        if (lane == 0)
            wkey[t & 1][wid] = ((unsigned long long)wmax << 32) |
                               (unsigned)(~best);
        __syncthreads();
        const ulonglong2* wk = (const ulonglong2*)wkey[t & 1];
        const ulonglong2 ka = wk[0], kb = wk[1];
        unsigned long long kk = ka.x;
        if (ka.y > kk) kk = ka.y;
        if (kb.x > kk) kk = kb.x;
        if (kb.y > kk) kk = kb.y;
        const int farthest = (int)(~(unsigned)kk) & (NPTS - 1);
        c4 = pxyz[farthest];
        cx = c4.x; cy = c4.y; cz = c4.z;
    }
    __syncthreads();
    float* ox = outx + b * 3 * NPOINT;
    for (int i = tid; i < NPOINT; i += 256) {
        const float4 c = orec[i];
        ox[i]              = c.x;
        ox[NPOINT + i]     = c.y;
        ox[2 * NPOINT + i] = c.z;
    }
}

// ---------------------------------------------------------------------------
// Ball query + fused moments + packed-bf16 feature store. One wave per query.
// R17: myidx moved global->LDS (it was kernel-local scratch; removes a
// global write+read round trip and the 1MB idxbuf).
// ---------------------------------------------------------------------------
__global__ __launch_bounds__(256) void ball_kernel(const float* __restrict__ xyz,
                                                   const float* __restrict__ pts,
                                                   const float* __restrict__ outx,
                                                   float* __restrict__ mom,
                                                   uint4* __restrict__ featbuf)
{
    __shared__ float red[4][42];
    __shared__ int smyidx[4][NSAMP];
    const int tid = threadIdx.x;
    const int w = blockIdx.x * 4 + (tid >> 6);
    const int lane = tid & 63, wid = tid >> 6;
    const int b = w >> 10, s = w & 1023;
    const float* base = xyz + b * 3 * NPTS;
    const float cx = outx[b * 3 * NPOINT + s];
    const float cy = outx[b * 3 * NPOINT + NPOINT + s];
    const float cz = outx[b * 3 * NPOINT + 2 * NPOINT + s];
    const float sumS = __fadd_rn(__fadd_rn(__fmul_rn(cx, cx), __fmul_rn(cy, cy)),
                                 __fmul_rn(cz, cz));
    int cnt = 0, first_n = -1;
    int* myidx = smyidx[wid];

    for (int chunk = 0; chunk < NPTS / 64 && cnt < NSAMP; ++chunk) {
        const int n = chunk * 64 + lane;
        float nx = base[n], ny = base[NPTS + n], nz = base[2 * NPTS + n];
        float sumN = __fadd_rn(__fadd_rn(__fmul_rn(nx, nx), __fmul_rn(ny, ny)),
                               __fmul_rn(nz, nz));
        float dot = __fadd_rn(__fadd_rn(__fmul_rn(cx, nx), __fmul_rn(cy, ny)),
                              __fmul_rn(cz, nz));
        float sq = __fsub_rn(__fadd_rn(sumS, sumN), __fmul_rn(2.0f, dot));
        bool keep = (sq <= RAD2);
        unsigned long long mask = __ballot(keep);
        if (first_n < 0 && mask) first_n = chunk * 64 + (int)__builtin_ctzll(mask);
        int pos = cnt + __popcll(mask & ((1ull << lane) - 1ull));
        if (keep && pos < NSAMP) myidx[pos] = n;
        cnt += __popcll(mask);
    }
    if (cnt < NSAMP) {
        if (lane >= cnt && lane < NSAMP) myidx[lane] = first_n;
    }

    // ---- fused moments + feature store for this wave's 32 rows ----
    float m[42];
#pragma unroll
    for (int i = 0; i < 42; ++i) m[i] = 0.f;
    if (lane < 32) {
        const int idx = myidx[lane];
        const float* pb = pts + b * 3 * NPTS;
        float f[6];
        f[0] = base[idx] - cx;
        f[1] = base[NPTS + idx] - cy;
        f[2] = base[2 * NPTS + idx] - cz;
        f[3] = pb[idx];
        f[4] = pb[NPTS + idx];
        f[5] = pb[2 * NPTS + idx];
        featbuf[w * NSAMP + lane] =
            make_uint4(pack2bf(f[0], f[1]), pack2bf(f[2], f[3]),
                       pack2bf(f[4], f[5]), 0u);
#pragma unroll
        for (int c = 0; c < 6; ++c) m[c] = f[c];
#pragma unroll
        for (int c = 0; c < 6; ++c)
#pragma unroll
            for (int d = 0; d < 6; ++d)
                m[6 + c * 6 + d] = f[c] * f[d];
    }
#pragma unroll
    for (int i = 0; i < 42; ++i) {
        float v = m[i];
        v += __shfl_xor(v, 1);  v += __shfl_xor(v, 2);  v += __shfl_xor(v, 4);
        v += __shfl_xor(v, 8);  v += __shfl_xor(v, 16); v += __shfl_xor(v, 32);
        m[i] = v;
    }
    if (lane == 0) {
#pragma unroll
        for (int i = 0; i < 42; ++i) red[wid][i] = m[i];
    }
    __syncthreads();
    if (tid < 42)
        atomicAdd(&mom[tid], red[0][tid] + red[1][tid] + red[2][tid] + red[3][tid]);
}

// bn0 from feature moments (biases cancel through BN shift; bilinear in W0)
__device__ __forceinline__ void compute_bn0(int o, const float* __restrict__ mom,
                                            const float* __restrict__ w0,
                                            const float* __restrict__ g,
                                            const float* __restrict__ be,
                                            float* __restrict__ sbn0)
{
    float w[6];
#pragma unroll
    for (int c = 0; c < 6; ++c) w[c] = w0[o * 6 + c];
    const float inv = 1.0f / (float)NROWS;
    float mean = 0.f;
#pragma unroll
    for (int c = 0; c < 6; ++c) mean = fmaf(w[c], mom[c], mean);
    mean *= inv;
    float ey2 = 0.f;
#pragma unroll
    for (int c = 0; c < 6; ++c) {
        float t = 0.f;
#pragma unroll
        for (int d = 0; d < 6; ++d) t = fmaf(w[d], mom[6 + c * 6 + d], t);
        ey2 = fmaf(w[c], t, ey2);
    }
    ey2 *= inv;
    const float var = ey2 - mean * mean;
    const float scale = g[o] * rsqrtf(var + 1e-5f);
    sbn0[o] = scale;
    sbn0[64 + o] = be[o] - mean * scale;
}

// ===========================================================================
// MFMA MLP kernels: 512 blocks x 512 rows (4 chunks of 128), weights staged
// once per block, stats in registers across chunks.
// mfma_f32_16x16x32_bf16: A[m=lane&15][k=q*8+j], B[k=q*8+j][n=lane&15],
// D[row=q*4+r][col=lane&15]  (q = lane>>4).
// R17: mlp1 optionally stores bf16(L1out) per group (32 rows x 64 ch, uint4-
// packed) so mlp2b can skip the L0/L1 recompute. stats1 stays computed from
// f32 acc1 -> bn1 coefficients bit-identical to the recompute path.
// ===========================================================================
#define XP  72
#define WP  72
#define W0P 40

// ---- mlp1: feat -> L0 -> bn0(inline from moments) -> L1 -> stats1 [+store] --
__global__ __launch_bounds__(256, 2) void mlp1_kernel(
    const uint4* __restrict__ featbuf,
    const float* __restrict__ w0, const float* __restrict__ mom,
    const float* __restrict__ g0, const float* __restrict__ be0,
    const float* __restrict__ w1, float* __restrict__ stats,
    uint4* __restrict__ l1store)
{
    __shared__ __align__(16) unsigned short sw0[64 * W0P];
    __shared__ __align__(16) unsigned short sw1[64 * WP];
    __shared__ __align__(16) unsigned short xb[4][32 * XP];
    __shared__ float sbn0[128];
    __shared__ float red[4][128];
    const int tid = threadIdx.x, lane = tid & 63, wid = tid >> 6;

    for (int i = tid; i < 64 * W0P / 2; i += 256) ((unsigned*)sw0)[i] = 0;
    if (tid < 64) compute_bn0(tid, mom, w0, g0, be0, sbn0);
    __syncthreads();
    for (int i = tid; i < 192; i += 256) {
        const int o = i / 3, c = (i % 3) * 2;
        *(unsigned*)&sw0[o * W0P + c] = pack2bf(w0[o * 6 + c], w0[o * 6 + c + 1]);
    }
    for (int i = tid; i < 2048; i += 256) {
        const int o = i >> 5, k = (i & 31) * 2;
        *(unsigned*)&sw1[o * WP + k] = pack2bf(w1[o * 64 + k], w1[o * 64 + k + 1]);
    }

    const int mh = lane & 15, q = lane >> 4;
    unsigned short* X = xb[wid];
    const int rbase = blockIdx.x * 512 + wid * 32;
    float sA[4] = {0.f, 0.f, 0.f, 0.f}, qA[4] = {0.f, 0.f, 0.f, 0.f};

    for (int c = 0; c < 4; ++c) {
        __syncthreads();
        if (lane < 32) {
            const int r = rbase + c * 128 + lane;
            uint4* xq = (uint4*)&xb[wid][lane * XP];
            xq[0] = featbuf[r];
            xq[1] = make_uint4(0u, 0u, 0u, 0u);
            xq[2] = make_uint4(0u, 0u, 0u, 0u);
            xq[3] = make_uint4(0u, 0u, 0u, 0u);
        }
        __syncthreads();
        // L0
        f32x4 acc0[2][4] = {};
        {
            bf16x8 a[2], bw[4];
#pragma unroll
            for (int mt = 0; mt < 2; ++mt)
                a[mt] = *(const bf16x8*)&X[(mt * 16 + mh) * XP + q * 8];
#pragma unroll
            for (int nt = 0; nt < 4; ++nt)
                bw[nt] = *(const bf16x8*)&sw0[(nt * 16 + mh) * W0P + q * 8];
#pragma unroll
            for (int mt = 0; mt < 2; ++mt)
#pragma unroll
                for (int nt = 0; nt < 4; ++nt)
                    acc0[mt][nt] = __builtin_amdgcn_mfma_f32_16x16x32_bf16(
                        a[mt], bw[nt], acc0[mt][nt], 0, 0, 0);
        }
        __syncthreads();
#pragma unroll
        for (int nt = 0; nt < 4; ++nt) {
            const int ch = nt * 16 + mh;
            const float sc = sbn0[ch], sh = sbn0[64 + ch];
#pragma unroll
            for (int mt = 0; mt < 2; ++mt)
#pragma unroll
                for (int rr = 0; rr < 4; ++rr) {
                    const float v = fmaxf(fmaf(acc0[mt][nt][rr], sc, sh), 0.0f);
                    X[(mt * 16 + q * 4 + rr) * XP + ch] = f2bf(v);
                }
        }
        __syncthreads();
        // L1
        f32x4 acc1[2][4] = {};
#pragma unroll
        for (int ks = 0; ks < 2; ++ks) {
            bf16x8 a[2], bw[4];
#pragma unroll
            for (int mt = 0; mt < 2; ++mt)
                a[mt] = *(const bf16x8*)&X[(mt * 16 + mh) * XP + ks * 32 + q * 8];
#pragma unroll
            for (int nt = 0; nt < 4; ++nt)
                bw[nt] = *(const bf16x8*)&sw1[(nt * 16 + mh) * WP + ks * 32 + q * 8];
#pragma unroll
            for (int mt = 0; mt < 2; ++mt)
#pragma unroll
                for (int nt = 0; nt < 4; ++nt)
                    acc1[mt][nt] = __builtin_amdgcn_mfma_f32_16x16x32_bf16(
                        a[mt], bw[nt], acc1[mt][nt], 0, 0, 0);
        }
        // stats from f32 acc1 (bit-identical to recompute path)
#pragma unroll
        for (int nt = 0; nt < 4; ++nt)
#pragma unroll
            for (int mt = 0; mt < 2; ++mt)
#pragma unroll
                for (int rr = 0; rr < 4; ++rr) {
                    const float v = acc1[mt][nt][rr];
                    sA[nt] += v;
                    qA[nt] = fmaf(v, v, qA[nt]);
                }
        if (l1store) {
            // stage bf16(L1out pre-BN) in the wave-private X region
            // (L1's reads of X are done: acc1 lives in registers)
#pragma unroll
            for (int nt = 0; nt < 4; ++nt) {
                const int ch = nt * 16 + mh;
#pragma unroll
                for (int mt = 0; mt < 2; ++mt)
#pragma unroll
                    for (int rr = 0; rr < 4; ++rr)
                        X[(mt * 16 + q * 4 + rr) * XP + ch] =
                            f2bf(acc1[mt][nt][rr]);
            }
            // wave-private: same-wave LDS write->read ordering via lgkmcnt
            uint4* dst = l1store +
                         (size_t)(blockIdx.x * 16 + c * 4 + wid) * 256;
#pragma unroll
            for (int k = 0; k < 4; ++k) {
                const int idx = lane * 4 + k;
                const int row = idx >> 3, c8 = (idx & 7) * 8;
                dst[idx] = *(const uint4*)&X[row * XP + c8];
            }
        }
    }
#pragma unroll
    for (int nt = 0; nt < 4; ++nt) {
        float s = sA[nt], qq = qA[nt];
        s += __shfl_xor(s, 16); qq += __shfl_xor(qq, 16);
        s += __shfl_xor(s, 32); qq += __shfl_xor(qq, 32);
        if (q == 0) {
            red[wid][nt * 16 + mh] = s;
            red[wid][64 + nt * 16 + mh] = qq;
        }
    }
    __syncthreads();
    if (tid < 128)
        atomicAdd(&stats[tid],
                  red[0][tid] + red[1][tid] + red[2][tid] + red[3][tid]);
}

// ---- mlp2b: l1buf -> bn1(in-register) -> L2 -> stats2 + max (lean path) ----
__global__ __launch_bounds__(256, 2) void mlp2b_kernel(
    const uint4* __restrict__ l1buf,
    const float* __restrict__ stats1,
    const float* __restrict__ g1, const float* __restrict__ be1,
    const float* __restrict__ w2,
    float* __restrict__ stats, float* __restrict__ gmax)
{
    __shared__ __align__(16) unsigned short sw2[128 * WP];
    __shared__ float sbn1[128];
    __shared__ float red[4][256];
    const int tid = threadIdx.x, lane = tid & 63, wid = tid >> 6;

    if (tid < 64) {
        const float inv = 1.0f / (float)NROWS;
        const float mean = stats1[tid] * inv;
        const float var = stats1[64 + tid] * inv - mean * mean;
        const float scale = g1[tid] * rsqrtf(var + 1e-5f);
        sbn1[tid] = scale;
        sbn1[64 + tid] = be1[tid] - mean * scale;
    }
    for (int i = tid; i < 4096; i += 256) {
        const int o = i >> 5, k = (i & 31) * 2;
        *(unsigned*)&sw2[o * WP + k] = pack2bf(w2[o * 64 + k], w2[o * 64 + k + 1]);
    }
    __syncthreads();

    const int mh = lane & 15, q = lane >> 4;
    // per-lane bn1 coefficients: channels ks*32 + q*8 + j (lane-invariant
    // across chunks and mt) -> preload once, zero LDS traffic in the loop
    float sc[2][8], sh[2][8];
#pragma unroll
    for (int ks = 0; ks < 2; ++ks)
#pragma unroll
        for (int j = 0; j < 8; ++j) {
            const int ch = ks * 32 + q * 8 + j;
            sc[ks][j] = sbn1[ch];
            sh[ks][j] = sbn1[64 + ch];
        }

    float sA[8], qA[8];
#pragma unroll
    for (int i = 0; i < 8; ++i) { sA[i] = 0.f; qA[i] = 0.f; }

    for (int c = 0; c < 4; ++c) {
        const int g = blockIdx.x * 16 + c * 4 + wid;
        const uint4* src = l1buf + (size_t)g * 256;
        bf16x8 a2[2][2];
#pragma unroll
        for (int mt = 0; mt < 2; ++mt)
#pragma unroll
            for (int ks = 0; ks < 2; ++ks) {
                const int row = mt * 16 + mh;
                const uint4 v = src[row * 8 + ks * 4 + q];
                const unsigned* pv = (const unsigned*)&v;
                unsigned r[4];
#pragma unroll
                for (int p = 0; p < 4; ++p) {
                    const unsigned u = pv[p];
                    const float f0 = __uint_as_float(u << 16);
                    const float f1 = __uint_as_float(u & 0xFFFF0000u);
                    const float v0 =
                        fmaxf(fmaf(f0, sc[ks][2 * p], sh[ks][2 * p]), 0.0f);
                    const float v1 =
                        fmaxf(fmaf(f1, sc[ks][2 * p + 1], sh[ks][2 * p + 1]),
                              0.0f);
                    r[p] = pack2bf(v0, v1);
                }
                const uint4 packed = make_uint4(r[0], r[1], r[2], r[3]);
                a2[mt][ks] = __builtin_bit_cast(bf16x8, packed);
            }
        // L2 + stats accumulate + per-group (32-row) max
#pragma unroll
        for (int nt = 0; nt < 8; ++nt) {
            f32x4 acc[2] = {};
#pragma unroll
            for (int ks = 0; ks < 2; ++ks) {
                const bf16x8 bw =
                    *(const bf16x8*)&sw2[(nt * 16 + mh) * WP + ks * 32 + q * 8];
#pragma unroll
                for (int mt = 0; mt < 2; ++mt)
                    acc[mt] = __builtin_amdgcn_mfma_f32_16x16x32_bf16(
                        a2[mt][ks], bw, acc[mt], 0, 0, 0);
            }
            float m = -3.0e38f;
#pragma unroll
            for (int mt = 0; mt < 2; ++mt)
#pragma unroll
                for (int rr = 0; rr < 4; ++rr) {
                    const float v = acc[mt][rr];
                    sA[nt] += v;
                    qA[nt] = fmaf(v, v, qA[nt]);
                    m = fmaxf(m, v);
                }
            m = fmaxf(m, __shfl_xor(m, 16));
            m = fmaxf(m, __shfl_xor(m, 32));
            if (q == 0) gmax[(nt * 16 + mh) * 8192 + g] = m;
        }
    }
#pragma unroll
    for (int nt = 0; nt < 8; ++nt) {
        float s = sA[nt], qq = qA[nt];
        s += __shfl_xor(s, 16); qq += __shfl_xor(qq, 16);
        s += __shfl_xor(s, 32); qq += __shfl_xor(qq, 32);
        if (q == 0) {
            red[wid][nt * 16 + mh] = s;
            red[wid][128 + nt * 16 + mh] = qq;
        }
    }
    __syncthreads();
    atomicAdd(&stats[tid],
              red[0][tid] + red[1][tid] + red[2][tid] + red[3][tid]);
}

// ---- mlp2: full recompute path (fallback when workspace too small) ---------
__global__ __launch_bounds__(256, 2) void mlp2_kernel(
    const uint4* __restrict__ featbuf,
    const float* __restrict__ w0, const float* __restrict__ mom,
    const float* __restrict__ g0, const float* __restrict__ be0,
    const float* __restrict__ w1, const float* __restrict__ stats1,
    const float* __restrict__ g1, const float* __restrict__ be1,
    const float* __restrict__ w2,
    float* __restrict__ stats, float* __restrict__ gmax)
{
    __shared__ __align__(16) unsigned short sw0[64 * W0P];
    __shared__ __align__(16) unsigned short sw1[64 * WP];
    __shared__ __align__(16) unsigned short sw2[128 * WP];
    __shared__ __align__(16) unsigned short xb[4][32 * XP];
    __shared__ float sbn0[128];
    __shared__ float sbn1[128];
    __shared__ float red[4][256];
    const int tid = threadIdx.x, lane = tid & 63, wid = tid >> 6;

    for (int i = tid; i < 64 * W0P / 2; i += 256) ((unsigned*)sw0)[i] = 0;
    if (tid < 64) {
        compute_bn0(tid, mom, w0, g0, be0, sbn0);
    } else if (tid < 128) {
        const int ch = tid - 64;
        const float inv = 1.0f / (float)NROWS;
        const float mean = stats1[ch] * inv;
        const float var = stats1[64 + ch] * inv - mean * mean;
        const float scale = g1[ch] * rsqrtf(var + 1e-5f);
        sbn1[ch] = scale;
        sbn1[64 + ch] = be1[ch] - mean * scale;
    }
    __syncthreads();
    for (int i = tid; i < 192; i += 256) {
        const int o = i / 3, c = (i % 3) * 2;
        *(unsigned*)&sw0[o * W0P + c] = pack2bf(w0[o * 6 + c], w0[o * 6 + c + 1]);
    }
    for (int i = tid; i < 2048; i += 256) {
        const int o = i >> 5, k = (i & 31) * 2;
        *(unsigned*)&sw1[o * WP + k] = pack2bf(w1[o * 64 + k], w1[o * 64 + k + 1]);
    }
    for (int i = tid; i < 4096; i += 256) {
        const int o = i >> 5, k = (i & 31) * 2;
        *(unsigned*)&sw2[o * WP + k] = pack2bf(w2[o * 64 + k], w2[o * 64 + k + 1]);
    }

    const int mh = lane & 15, q = lane >> 4;
    unsigned short* X = xb[wid];
    const int rbase = blockIdx.x * 512 + wid * 32;
    float sA[8], qA[8];
#pragma unroll
    for (int i = 0; i < 8; ++i) { sA[i] = 0.f; qA[i] = 0.f; }

    for (int c = 0; c < 4; ++c) {
        __syncthreads();
        if (lane < 32) {
            const int r = rbase + c * 128 + lane;
            uint4* xq = (uint4*)&xb[wid][lane * XP];
            xq[0] = featbuf[r];
            xq[1] = make_uint4(0u, 0u, 0u, 0u);
            xq[2] = make_uint4(0u, 0u, 0u, 0u);
            xq[3] = make_uint4(0u, 0u, 0u, 0u);
        }
        __syncthreads();
        // L0
        f32x4 acc0[2][4] = {};
        {
            bf16x8 a[2], bw[4];
#pragma unroll
            for (int mt = 0; mt < 2; ++mt)
                a[mt] = *(const bf16x8*)&X[(mt * 16 + mh) * XP + q * 8];
#pragma unroll
            for (int nt = 0; nt < 4; ++nt)
                bw[nt] = *(const bf16x8*)&sw0[(nt * 16 + mh) * W0P + q * 8];
#pragma unroll
            for (int mt = 0; mt < 2; ++mt)
#pragma unroll
                for (int nt = 0; nt < 4; ++nt)
                    acc0[mt][nt] = __builtin_amdgcn_mfma_f32_16x16x32_bf16(
                        a[mt], bw[nt], acc0[mt][nt], 0, 0, 0);
        }
        __syncthreads();
#pragma unroll
        for (int nt = 0; nt < 4; ++nt) {
            const int ch = nt * 16 + mh;
            const float sc = sbn0[ch], sh = sbn0[64 + ch];
#pragma unroll
            for (int mt = 0; mt < 2; ++mt)
#pragma unroll
                for (int rr = 0; rr < 4; ++rr) {
                    const float v = fmaxf(fmaf(acc0[mt][nt][rr], sc, sh), 0.0f);
                    X[(mt * 16 + q * 4 + rr) * XP + ch] = f2bf(v);
                }
        }
        __syncthreads();
        // L1
        f32x4 acc1[2][4] = {};
#pragma unroll
        for (int ks = 0; ks < 2; ++ks) {
            bf16x8 a[2], bw[4];
#pragma unroll
            for (int mt = 0; mt < 2; ++mt)
                a[mt] = *(const bf16x8*)&X[(mt * 16 + mh) * XP + ks * 32 + q * 8];
#pragma unroll
            for (int nt = 0; nt < 4; ++nt)
                bw[nt] = *(const bf16x8*)&sw1[(nt * 16 + mh) * WP + ks * 32 + q * 8];
#pragma unroll
            for (int mt = 0; mt < 2; ++mt)
#pragma unroll
                for (int nt = 0; nt < 4; ++nt)
                    acc1[mt][nt] = __builtin_amdgcn_mfma_f32_16x16x32_bf16(
                        a[mt], bw[nt], acc1[mt][nt], 0, 0, 0);
        }
        __syncthreads();
#pragma unroll
        for (int nt = 0; nt < 4; ++nt) {
            const int ch = nt * 16 + mh;
            const float sc = sbn1[ch], sh = sbn1[64 + ch];
#pragma unroll
            for (int mt = 0; mt < 2; ++mt)
#pragma unroll
                for (int rr = 0; rr < 4; ++rr) {
                    const float v = fmaxf(fmaf(acc1[mt][nt][rr], sc, sh), 0.0f);
                    X[(mt * 16 + q * 4 + rr) * XP + ch] = f2bf(v);
                }
        }
        __syncthreads();
        // L2 + stats accumulate + per-group (32-row) max
        const int g = blockIdx.x * 16 + c * 4 + wid;
        bf16x8 a2[2][2];
#pragma unroll
        for (int mt = 0; mt < 2; ++mt)
#pragma unroll
            for (int ks = 0; ks < 2; ++ks)
                a2[mt][ks] = *(const bf16x8*)&X[(mt * 16 + mh) * XP + ks * 32 + q * 8];
#pragma unroll
        for (int nt = 0; nt < 8; ++nt) {
            f32x4 acc[2] = {};
#pragma unroll
            for (int ks = 0; ks < 2; ++ks) {
                const bf16x8 bw = *(const bf16x8*)&sw2[(nt * 16 + mh) * WP + ks * 32 + q * 8];
#pragma unroll
                for (int mt = 0; mt < 2; ++mt)
                    acc[mt] = __builtin_amdgcn_mfma_f32_16x16x32_bf16(
                        a2[mt][ks], bw, acc[mt], 0, 0, 0);
            }
            float m = -3.0e38f;
#pragma unroll
            for (int mt = 0; mt < 2; ++mt)
#pragma unroll
                for (int rr = 0; rr < 4; ++rr) {
                    const float v = acc[mt][rr];
                    sA[nt] += v;
                    qA[nt] = fmaf(v, v, qA[nt]);
                    m = fmaxf(m, v);
                }
            m = fmaxf(m, __shfl_xor(m, 16));
            m = fmaxf(m, __shfl_xor(m, 32));
            if (q == 0) gmax[(nt * 16 + mh) * 8192 + g] = m;
        }
    }
#pragma unroll
    for (int nt = 0; nt < 8; ++nt) {
        float s = sA[nt], qq = qA[nt];
        s += __shfl_xor(s, 16); qq += __shfl_xor(qq, 16);
        s += __shfl_xor(s, 32); qq += __shfl_xor(qq, 32);
        if (q == 0) {
            red[wid][nt * 16 + mh] = s;
            red[wid][128 + nt * 16 + mh] = qq;
        }
    }
    __syncthreads();
    atomicAdd(&stats[tid],
              red[0][tid] + red[1][tid] + red[2][tid] + red[3][tid]);
}

// ---------------------------------------------------------------------------
// final: bn2 computed inline from stats2; out2[b,o,s] = relu(bn2(gmax))
// ---------------------------------------------------------------------------
__global__ __launch_bounds__(256) void final_kernel(const float* __restrict__ gmax,
                                                    const float* __restrict__ stats2,
                                                    const float* __restrict__ g2,
                                                    const float* __restrict__ be2,
                                                    float* __restrict__ out2)
{
    __shared__ float sbn[256];
    const int tid = threadIdx.x;
    if (tid < 128) {
        const float inv = 1.0f / (float)NROWS;
        const float mean = stats2[tid] * inv;
        const float var = stats2[128 + tid] * inv - mean * mean;
        const float scale = g2[tid] * rsqrtf(var + 1e-5f);
        sbn[tid] = scale;
        sbn[128 + tid] = be2[tid] - mean * scale;
    }
    __syncthreads();
    const int t = blockIdx.x * 256 + tid;
    const int s = t & 1023;
    const int o = (t >> 10) & 127;
    const int b = t >> 17;
    const int g = (b << 10) | s;
    float v = gmax[o * 8192 + g];
    v = fmaf(v, sbn[o], sbn[128 + o]);
    out2[t] = fmaxf(v, 0.0f);
}

// ---------------------------------------------------------------------------
extern "C" void kernel_launch(void* const* d_in, const int* in_sizes, int n_in,
                              void* d_out, int out_size, void* d_ws, size_t ws_size,
                              hipStream_t stream)
{
    const float* xyz = (const float*)d_in[0];
    const float* pts = (const float*)d_in[1];
    const float* w0  = (const float*)d_in[2];
    const float* g0  = (const float*)d_in[4];
    const float* be0 = (const float*)d_in[5];
    const float* w1  = (const float*)d_in[6];
    const float* g1  = (const float*)d_in[8];
    const float* be1 = (const float*)d_in[9];
    const float* w2  = (const float*)d_in[10];
    const float* g2  = (const float*)d_in[12];
    const float* be2 = (const float*)d_in[13];

    float* out_xyz = (float*)d_out;             // (B,3,1024)
    float* out2    = out_xyz + 8 * 3 * NPOINT;  // (B,128,1024)

    char* wsb = (char*)d_ws;
    float* stats   = (float*)(wsb + 32768 + 1048576);   // 512 floats
    float* gmax    = stats + 1024;                      // 128*8192 floats (4 MB)
    uint4* featbuf = (uint4*)(gmax + 128 * 8192);       // 262144 uint4 (4 MB)
    uint4* l1buf   = featbuf + NROWS;                   // 8192*256 uint4 (32 MB)

    float* mom    = stats;                              // 42 floats
    float* stats1 = stats + 128;
    float* stats2 = stats + 256;

    // end of l1buf = 32768 + 1MB + 4KB + 4MB + 4MB + 32MB ≈ 43.03 MB
    const bool bigws = ws_size >= (size_t)43100000;

    hipMemsetAsync(stats, 0, 512 * sizeof(float), stream);

    fps_kernel<<<8, 256, 0, stream>>>(xyz, out_xyz);
    ball_kernel<<<2048, 256, 0, stream>>>(xyz, pts, out_xyz, mom, featbuf);
    if (bigws) {
        mlp1_kernel<<<512, 256, 0, stream>>>(featbuf, w0, mom, g0, be0,
                                             w1, stats1, l1buf);
        mlp2b_kernel<<<512, 256, 0, stream>>>(l1buf, stats1, g1, be1,
                                              w2, stats2, gmax);
    } else {
        mlp1_kernel<<<512, 256, 0, stream>>>(featbuf, w0, mom, g0, be0,
                                             w1, stats1, nullptr);
        mlp2_kernel<<<512, 256, 0, stream>>>(featbuf, w0, mom, g0, be0,
                                             w1, stats1, g1, be1,
                                             w2, stats2, gmax);
    }
    final_kernel<<<4096, 256, 0, stream>>>(gmax, stats2, g2, be2, out2);
}

// Round 4
// 774.252 us; speedup vs baseline: 1.3383x; 1.0245x over previous
//
#include <hip/hip_runtime.h>
#include <stdint.h>

#define NPTS   4096
#define NPOINT 1024
#define NSAMP  32
#define NROWS  262144   // B*NPOINT*NSAMP
#define RAD2   0.04f

typedef float v2f __attribute__((ext_vector_type(2)));
typedef __attribute__((ext_vector_type(8))) short bf16x8;
typedef __attribute__((ext_vector_type(4))) float f32x4;

// bf16 round-to-nearest-even
__device__ __forceinline__ unsigned short f2bf(float x) {
    unsigned u = __float_as_uint(x);
    return (unsigned short)((u + 0x7FFFu + ((u >> 16) & 1u)) >> 16);
}
__device__ __forceinline__ unsigned pack2bf(float a, float b) {
    return (unsigned)f2bf(a) | ((unsigned)f2bf(b) << 16);
}

// fused-DPP max helper (single-use feed -> v_max_f32_dpp)
#define DPPMAX(v, C)                                                           \
    fmaxf(__int_as_float(__builtin_amdgcn_update_dpp(                          \
              0, __float_as_int(v), C, 0xf, 0xf, true)),                       \
          (v))
// fused-DPP add helper (row_shr tree sum; bound_ctrl 0-fill = identity)
#define DPPADD(v, C)                                                           \
    (__int_as_float(__builtin_amdgcn_update_dpp(                               \
         0, __float_as_int(v), C, 0xf, 0xf, true)) +                           \
     (v))

// ---------------------------------------------------------------------------
// FPS: frozen at R14 state (587us). 8 structural variants tried, all >=586.
// DO NOT TOUCH: 132 VGPRs keeps the 64-reg point state resident.
// ---------------------------------------------------------------------------
__global__ __launch_bounds__(256) void fps_kernel(const float* __restrict__ xyz,
                                                  float* __restrict__ outx)
{
    __shared__ __align__(16) float4 pxyz[NPTS];
    __shared__ __align__(16) float4 orec[NPOINT];
    __shared__ __align__(16) unsigned long long wkey[2][4];
    const int b = blockIdx.x, tid = threadIdx.x;
    const int lane = tid & 63, wid = tid >> 6;
    const float* base = xyz + b * 3 * NPTS;

    float Xs[16], Ys[16], Zs[16];
#pragma unroll
    for (int j = 0; j < 16; ++j) {
        const int n = j * 256 + tid;
        Xs[j] = base[n];
        Ys[j] = base[NPTS + n];
        Zs[j] = base[2 * NPTS + n];
        pxyz[n] = make_float4(Xs[j], Ys[j], Zs[j], 0.0f);
    }
    v2f X2[8], Y2[8], Z2[8], D2[8];
#pragma unroll
    for (int j = 0; j < 8; ++j) {
        X2[j] = (v2f){Xs[2 * j], Xs[2 * j + 1]};
        Y2[j] = (v2f){Ys[2 * j], Ys[2 * j + 1]};
        Z2[j] = (v2f){Zs[2 * j], Zs[2 * j + 1]};
        D2[j] = (v2f){1e10f, 1e10f};
    }
    __syncthreads();
    float4 c4 = pxyz[0];
    float cx = c4.x, cy = c4.y, cz = c4.z;

    for (int t = 0; t < NPOINT; ++t) {
        if (tid == 0) orec[t] = make_float4(cx, cy, cz, 0.0f);
        const v2f cxv = (v2f){cx, cx}, cyv = (v2f){cy, cy}, czv = (v2f){cz, cz};
        float bv = -1.0f; int bi = 0;
#pragma unroll
        for (int j = 0; j < 8; ++j) {
            v2f nd;
            {
#pragma clang fp contract(off)
                const v2f dx = X2[j] - cxv;
                const v2f dy = Y2[j] - cyv;
                const v2f dz = Z2[j] - czv;
                const v2f m0 = dx * dx;
                const v2f m1 = dy * dy;
                const v2f m2 = dz * dz;
                const v2f d = (m0 + m1) + m2;
                nd = __builtin_elementwise_min(D2[j], d);
            }
            D2[j] = nd;
            // ascending indices + strict > keep the first occurrence
            if (nd.x > bv) { bv = nd.x; bi = j * 512 + tid; }
            if (nd.y > bv) { bv = nd.y; bi = j * 512 + 256 + tid; }
        }
        // value-first fused-DPP max
        float rv = bv;                       // bv >= 0 (bound_ctrl 0-fill safe)
        rv = DPPMAX(rv, 0x111);              // row_shr:1
        rv = DPPMAX(rv, 0x112);              // row_shr:2
        rv = DPPMAX(rv, 0x114);              // row_shr:4
        rv = DPPMAX(rv, 0x118);              // row_shr:8
        rv = DPPMAX(rv, 0x142);              // row_bcast:15
        rv = DPPMAX(rv, 0x143);              // row_bcast:31
        const unsigned wmax =
            (unsigned)__builtin_amdgcn_readlane(__float_as_int(rv), 63);
        // index resolution: ballot + scalar min over matching lanes
        unsigned long long mask = __ballot(__float_as_uint(bv) == wmax);
        unsigned best =
            (unsigned)__builtin_amdgcn_readlane(bi, (int)__builtin_ctzll(mask));
        mask &= mask - 1ull;
        while (mask) {
            const unsigned cand = (unsigned)__builtin_amdgcn_readlane(
                bi, (int)__builtin_ctzll(mask));
            best = cand < best ? cand : best;
            mask &= mask - 1ull;
        }
        if (lane == 0)
            wkey[t & 1][wid] = ((unsigned long long)wmax << 32) |
                               (unsigned)(~best);
        __syncthreads();
        const ulonglong2* wk = (const ulonglong2*)wkey[t & 1];
        const ulonglong2 ka = wk[0], kb = wk[1];
        unsigned long long kk = ka.x;
        if (ka.y > kk) kk = ka.y;
        if (kb.x > kk) kk = kb.x;
        if (kb.y > kk) kk = kb.y;
        const int farthest = (int)(~(unsigned)kk) & (NPTS - 1);
        c4 = pxyz[farthest];
        cx = c4.x; cy = c4.y; cz = c4.z;
    }
    __syncthreads();
    float* ox = outx + b * 3 * NPOINT;
    for (int i = tid; i < NPOINT; i += 256) {
        const float4 c = orec[i];
        ox[i]              = c.x;
        ox[NPOINT + i]     = c.y;
        ox[2 * NPOINT + i] = c.z;
    }
}

// ---------------------------------------------------------------------------
// Ball query + fused moments + packed-bf16 feature store. One wave per query.
// R18: (a) software prefetch of chunk n+1 before the ballot chain (load
// latency hid under the dependent cnt/ballot update); (b) moment reduction
// via row_shr DPP adds (VALU pipe) + single xor-16 shuffle: DS ops drop
// 252->42 per wave; xor-32 dropped (lanes 32-63 hold zeros, only lane 0's
// value is consumed). Reassociation shifts bn0 stats by <=1 ulp.
// ---------------------------------------------------------------------------
__global__ __launch_bounds__(256) void ball_kernel(const float* __restrict__ xyz,
                                                   const float* __restrict__ pts,
                                                   const float* __restrict__ outx,
                                                   float* __restrict__ mom,
                                                   uint4* __restrict__ featbuf)
{
    __shared__ float red[4][42];
    __shared__ int smyidx[4][NSAMP];
    const int tid = threadIdx.x;
    const int w = blockIdx.x * 4 + (tid >> 6);
    const int lane = tid & 63, wid = tid >> 6;
    const int b = w >> 10, s = w & 1023;
    const float* base = xyz + b * 3 * NPTS;
    const float cx = outx[b * 3 * NPOINT + s];
    const float cy = outx[b * 3 * NPOINT + NPOINT + s];
    const float cz = outx[b * 3 * NPOINT + 2 * NPOINT + s];
    const float sumS = __fadd_rn(__fadd_rn(__fmul_rn(cx, cx), __fmul_rn(cy, cy)),
                                 __fmul_rn(cz, cz));
    int cnt = 0, first_n = -1;
    int* myidx = smyidx[wid];

    // prefetch chunk 0
    float nx = base[lane], ny = base[NPTS + lane], nz = base[2 * NPTS + lane];
    for (int chunk = 0; chunk < NPTS / 64 && cnt < NSAMP; ++chunk) {
        const float x = nx, y = ny, z = nz;
        if (chunk + 1 < NPTS / 64) {
            const int nn = (chunk + 1) * 64 + lane;
            nx = base[nn]; ny = base[NPTS + nn]; nz = base[2 * NPTS + nn];
        }
        const int n = chunk * 64 + lane;
        float sumN = __fadd_rn(__fadd_rn(__fmul_rn(x, x), __fmul_rn(y, y)),
                               __fmul_rn(z, z));
        float dot = __fadd_rn(__fadd_rn(__fmul_rn(cx, x), __fmul_rn(cy, y)),
                              __fmul_rn(cz, z));
        float sq = __fsub_rn(__fadd_rn(sumS, sumN), __fmul_rn(2.0f, dot));
        bool keep = (sq <= RAD2);
        unsigned long long mask = __ballot(keep);
        if (first_n < 0 && mask) first_n = chunk * 64 + (int)__builtin_ctzll(mask);
        int pos = cnt + __popcll(mask & ((1ull << lane) - 1ull));
        if (keep && pos < NSAMP) myidx[pos] = n;
        cnt += __popcll(mask);
    }
    if (cnt < NSAMP) {
        if (lane >= cnt && lane < NSAMP) myidx[lane] = first_n;
    }

    // ---- fused moments + feature store for this wave's 32 rows ----
    float m[42];
#pragma unroll
    for (int i = 0; i < 42; ++i) m[i] = 0.f;
    if (lane < 32) {
        const int idx = myidx[lane];
        const float* pb = pts + b * 3 * NPTS;
        float f[6];
        f[0] = base[idx] - cx;
        f[1] = base[NPTS + idx] - cy;
        f[2] = base[2 * NPTS + idx] - cz;
        f[3] = pb[idx];
        f[4] = pb[NPTS + idx];
        f[5] = pb[2 * NPTS + idx];
        featbuf[w * NSAMP + lane] =
            make_uint4(pack2bf(f[0], f[1]), pack2bf(f[2], f[3]),
                       pack2bf(f[4], f[5]), 0u);
#pragma unroll
        for (int c = 0; c < 6; ++c) m[c] = f[c];
#pragma unroll
        for (int c = 0; c < 6; ++c)
#pragma unroll
            for (int d = 0; d < 6; ++d)
                m[6 + c * 6 + d] = f[c] * f[d];
    }
    // row_shr DPP tree: lane0/lane16 hold row-of-16 sums; one xor-16 shuffle
    // folds lanes 16-31 into lane 0 (lanes 32-63 are zero, ignored).
#pragma unroll
    for (int i = 0; i < 42; ++i) {
        float v = m[i];
        v = DPPADD(v, 0x111);   // row_shr:1
        v = DPPADD(v, 0x112);   // row_shr:2
        v = DPPADD(v, 0x114);   // row_shr:4
        v = DPPADD(v, 0x118);   // row_shr:8
        v += __shfl_xor(v, 16);
        m[i] = v;
    }
    if (lane == 0) {
#pragma unroll
        for (int i = 0; i < 42; ++i) red[wid][i] = m[i];
    }
    __syncthreads();
    if (tid < 42)
        atomicAdd(&mom[tid], red[0][tid] + red[1][tid] + red[2][tid] + red[3][tid]);
}

// bn0 from feature moments (biases cancel through BN shift; bilinear in W0)
__device__ __forceinline__ void compute_bn0(int o, const float* __restrict__ mom,
                                            const float* __restrict__ w0,
                                            const float* __restrict__ g,
                                            const float* __restrict__ be,
                                            float* __restrict__ sbn0)
{
    float w[6];
#pragma unroll
    for (int c = 0; c < 6; ++c) w[c] = w0[o * 6 + c];
    const float inv = 1.0f / (float)NROWS;
    float mean = 0.f;
#pragma unroll
    for (int c = 0; c < 6; ++c) mean = fmaf(w[c], mom[c], mean);
    mean *= inv;
    float ey2 = 0.f;
#pragma unroll
    for (int c = 0; c < 6; ++c) {
        float t = 0.f;
#pragma unroll
        for (int d = 0; d < 6; ++d) t = fmaf(w[d], mom[6 + c * 6 + d], t);
        ey2 = fmaf(w[c], t, ey2);
    }
    ey2 *= inv;
    const float var = ey2 - mean * mean;
    const float scale = g[o] * rsqrtf(var + 1e-5f);
    sbn0[o] = scale;
    sbn0[64 + o] = be[o] - mean * scale;
}

// ===========================================================================
// MFMA MLP kernels: 512 blocks x 512 rows (4 chunks of 128), weights staged
// once per block, stats in registers across chunks.
// mfma_f32_16x16x32_bf16: A[m=lane&15][k=q*8+j], B[k=q*8+j][n=lane&15],
// D[row=q*4+r][col=lane&15]  (q = lane>>4).
// R18: mlp1 chunk-loop barriers REMOVED — xb[wid] is wave-private (stage,
// L0-read, bn0-store, L1-read all within the wave's 32xXP region); same-wave
// LDS ordering via the in-order DS pipe (pattern proven by R17 l1store).
// Two barriers remain: after weight/sbn0 staging, before final reduce.
// featbuf chunk c+1 is prefetched to registers while chunk c computes.
// ===========================================================================
#define XP  72
#define WP  72
#define W0P 40

// ---- mlp1: feat -> L0 -> bn0(inline from moments) -> L1 -> stats1 [+store] --
__global__ __launch_bounds__(256, 2) void mlp1_kernel(
    const uint4* __restrict__ featbuf,
    const float* __restrict__ w0, const float* __restrict__ mom,
    const float* __restrict__ g0, const float* __restrict__ be0,
    const float* __restrict__ w1, float* __restrict__ stats,
    uint4* __restrict__ l1store)
{
    __shared__ __align__(16) unsigned short sw0[64 * W0P];
    __shared__ __align__(16) unsigned short sw1[64 * WP];
    __shared__ __align__(16) unsigned short xb[4][32 * XP];
    __shared__ float sbn0[128];
    __shared__ float red[4][128];
    const int tid = threadIdx.x, lane = tid & 63, wid = tid >> 6;

    for (int i = tid; i < 64 * W0P / 2; i += 256) ((unsigned*)sw0)[i] = 0;
    if (tid < 64) compute_bn0(tid, mom, w0, g0, be0, sbn0);
    __syncthreads();
    for (int i = tid; i < 192; i += 256) {
        const int o = i / 3, c = (i % 3) * 2;
        *(unsigned*)&sw0[o * W0P + c] = pack2bf(w0[o * 6 + c], w0[o * 6 + c + 1]);
    }
    for (int i = tid; i < 2048; i += 256) {
        const int o = i >> 5, k = (i & 31) * 2;
        *(unsigned*)&sw1[o * WP + k] = pack2bf(w1[o * 64 + k], w1[o * 64 + k + 1]);
    }
    __syncthreads();   // weights + sbn0 visible to all waves

    const int mh = lane & 15, q = lane >> 4;
    unsigned short* X = xb[wid];
    const int rbase = blockIdx.x * 512 + wid * 32;
    float sA[4] = {0.f, 0.f, 0.f, 0.f}, qA[4] = {0.f, 0.f, 0.f, 0.f};

    // prefetch chunk 0
    uint4 preg = make_uint4(0u, 0u, 0u, 0u);
    if (lane < 32) preg = featbuf[rbase + lane];

    for (int c = 0; c < 4; ++c) {
        if (lane < 32) {
            uint4* xq = (uint4*)&xb[wid][lane * XP];
            xq[0] = preg;
            xq[1] = make_uint4(0u, 0u, 0u, 0u);
            xq[2] = make_uint4(0u, 0u, 0u, 0u);
            xq[3] = make_uint4(0u, 0u, 0u, 0u);
            if (c < 3) preg = featbuf[rbase + (c + 1) * 128 + lane];
        }
        // L0 (same-wave LDS: DS pipe in-order; compiler inserts lgkmcnt)
        f32x4 acc0[2][4] = {};
        {
            bf16x8 a[2], bw[4];
#pragma unroll
            for (int mt = 0; mt < 2; ++mt)
                a[mt] = *(const bf16x8*)&X[(mt * 16 + mh) * XP + q * 8];
#pragma unroll
            for (int nt = 0; nt < 4; ++nt)
                bw[nt] = *(const bf16x8*)&sw0[(nt * 16 + mh) * W0P + q * 8];
#pragma unroll
            for (int mt = 0; mt < 2; ++mt)
#pragma unroll
                for (int nt = 0; nt < 4; ++nt)
                    acc0[mt][nt] = __builtin_amdgcn_mfma_f32_16x16x32_bf16(
                        a[mt], bw[nt], acc0[mt][nt], 0, 0, 0);
        }
#pragma unroll
        for (int nt = 0; nt < 4; ++nt) {
            const int ch = nt * 16 + mh;
            const float sc = sbn0[ch], sh = sbn0[64 + ch];
#pragma unroll
            for (int mt = 0; mt < 2; ++mt)
#pragma unroll
                for (int rr = 0; rr < 4; ++rr) {
                    const float v = fmaxf(fmaf(acc0[mt][nt][rr], sc, sh), 0.0f);
                    X[(mt * 16 + q * 4 + rr) * XP + ch] = f2bf(v);
                }
        }
        // L1
        f32x4 acc1[2][4] = {};
#pragma unroll
        for (int ks = 0; ks < 2; ++ks) {
            bf16x8 a[2], bw[4];
#pragma unroll
            for (int mt = 0; mt < 2; ++mt)
                a[mt] = *(const bf16x8*)&X[(mt * 16 + mh) * XP + ks * 32 + q * 8];
#pragma unroll
            for (int nt = 0; nt < 4; ++nt)
                bw[nt] = *(const bf16x8*)&sw1[(nt * 16 + mh) * WP + ks * 32 + q * 8];
#pragma unroll
            for (int mt = 0; mt < 2; ++mt)
#pragma unroll
                for (int nt = 0; nt < 4; ++nt)
                    acc1[mt][nt] = __builtin_amdgcn_mfma_f32_16x16x32_bf16(
                        a[mt], bw[nt], acc1[mt][nt], 0, 0, 0);
        }
        // stats from f32 acc1 (bit-identical to recompute path)
#pragma unroll
        for (int nt = 0; nt < 4; ++nt)
#pragma unroll
            for (int mt = 0; mt < 2; ++mt)
#pragma unroll
                for (int rr = 0; rr < 4; ++rr) {
                    const float v = acc1[mt][nt][rr];
                    sA[nt] += v;
                    qA[nt] = fmaf(v, v, qA[nt]);
                }
        if (l1store) {
            // stage bf16(L1out pre-BN) in the wave-private X region
#pragma unroll
            for (int nt = 0; nt < 4; ++nt) {
                const int ch = nt * 16 + mh;
#pragma unroll
                for (int mt = 0; mt < 2; ++mt)
#pragma unroll
                    for (int rr = 0; rr < 4; ++rr)
                        X[(mt * 16 + q * 4 + rr) * XP + ch] =
                            f2bf(acc1[mt][nt][rr]);
            }
            // wave-private: same-wave LDS write->read ordering via DS pipe
            uint4* dst = l1store +
                         (size_t)(blockIdx.x * 16 + c * 4 + wid) * 256;
#pragma unroll
            for (int k = 0; k < 4; ++k) {
                const int idx = lane * 4 + k;
                const int row = idx >> 3, c8 = (idx & 7) * 8;
                dst[idx] = *(const uint4*)&X[row * XP + c8];
            }
        }
    }
#pragma unroll
    for (int nt = 0; nt < 4; ++nt) {
        float s = sA[nt], qq = qA[nt];
        s += __shfl_xor(s, 16); qq += __shfl_xor(qq, 16);
        s += __shfl_xor(s, 32); qq += __shfl_xor(qq, 32);
        if (q == 0) {
            red[wid][nt * 16 + mh] = s;
            red[wid][64 + nt * 16 + mh] = qq;
        }
    }
    __syncthreads();
    if (tid < 128)
        atomicAdd(&stats[tid],
                  red[0][tid] + red[1][tid] + red[2][tid] + red[3][tid]);
}

// ---- mlp2b: l1buf -> bn1(in-register) -> L2 -> stats2 + max (lean path) ----
__global__ __launch_bounds__(256, 2) void mlp2b_kernel(
    const uint4* __restrict__ l1buf,
    const float* __restrict__ stats1,
    const float* __restrict__ g1, const float* __restrict__ be1,
    const float* __restrict__ w2,
    float* __restrict__ stats, float* __restrict__ gmax)
{
    __shared__ __align__(16) unsigned short sw2[128 * WP];
    __shared__ float sbn1[128];
    __shared__ float red[4][256];
    const int tid = threadIdx.x, lane = tid & 63, wid = tid >> 6;

    if (tid < 64) {
        const float inv = 1.0f / (float)NROWS;
        const float mean = stats1[tid] * inv;
        const float var = stats1[64 + tid] * inv - mean * mean;
        const float scale = g1[tid] * rsqrtf(var + 1e-5f);
        sbn1[tid] = scale;
        sbn1[64 + tid] = be1[tid] - mean * scale;
    }
    for (int i = tid; i < 4096; i += 256) {
        const int o = i >> 5, k = (i & 31) * 2;
        *(unsigned*)&sw2[o * WP + k] = pack2bf(w2[o * 64 + k], w2[o * 64 + k + 1]);
    }
    __syncthreads();

    const int mh = lane & 15, q = lane >> 4;
    // per-lane bn1 coefficients: channels ks*32 + q*8 + j (lane-invariant
    // across chunks and mt) -> preload once, zero LDS traffic in the loop
    float sc[2][8], sh[2][8];
#pragma unroll
    for (int ks = 0; ks < 2; ++ks)
#pragma unroll
        for (int j = 0; j < 8; ++j) {
            const int ch = ks * 32 + q * 8 + j;
            sc[ks][j] = sbn1[ch];
            sh[ks][j] = sbn1[64 + ch];
        }

    float sA[8], qA[8];
#pragma unroll
    for (int i = 0; i < 8; ++i) { sA[i] = 0.f; qA[i] = 0.f; }

    for (int c = 0; c < 4; ++c) {
        const int g = blockIdx.x * 16 + c * 4 + wid;
        const uint4* src = l1buf + (size_t)g * 256;
        bf16x8 a2[2][2];
#pragma unroll
        for (int mt = 0; mt < 2; ++mt)
#pragma unroll
            for (int ks = 0; ks < 2; ++ks) {
                const int row = mt * 16 + mh;
                const uint4 v = src[row * 8 + ks * 4 + q];
                const unsigned* pv = (const unsigned*)&v;
                unsigned r[4];
#pragma unroll
                for (int p = 0; p < 4; ++p) {
                    const unsigned u = pv[p];
                    const float f0 = __uint_as_float(u << 16);
                    const float f1 = __uint_as_float(u & 0xFFFF0000u);
                    const float v0 =
                        fmaxf(fmaf(f0, sc[ks][2 * p], sh[ks][2 * p]), 0.0f);
                    const float v1 =
                        fmaxf(fmaf(f1, sc[ks][2 * p + 1], sh[ks][2 * p + 1]),
                              0.0f);
                    r[p] = pack2bf(v0, v1);
                }
                const uint4 packed = make_uint4(r[0], r[1], r[2], r[3]);
                a2[mt][ks] = __builtin_bit_cast(bf16x8, packed);
            }
        // L2 + stats accumulate + per-group (32-row) max
#pragma unroll
        for (int nt = 0; nt < 8; ++nt) {
            f32x4 acc[2] = {};
#pragma unroll
            for (int ks = 0; ks < 2; ++ks) {
                const bf16x8 bw =
                    *(const bf16x8*)&sw2[(nt * 16 + mh) * WP + ks * 32 + q * 8];
#pragma unroll
                for (int mt = 0; mt < 2; ++mt)
                    acc[mt] = __builtin_amdgcn_mfma_f32_16x16x32_bf16(
                        a2[mt][ks], bw, acc[mt], 0, 0, 0);
            }
            float m = -3.0e38f;
#pragma unroll
            for (int mt = 0; mt < 2; ++mt)
#pragma unroll
                for (int rr = 0; rr < 4; ++rr) {
                    const float v = acc[mt][rr];
                    sA[nt] += v;
                    qA[nt] = fmaf(v, v, qA[nt]);
                    m = fmaxf(m, v);
                }
            m = fmaxf(m, __shfl_xor(m, 16));
            m = fmaxf(m, __shfl_xor(m, 32));
            if (q == 0) gmax[(nt * 16 + mh) * 8192 + g] = m;
        }
    }
#pragma unroll
    for (int nt = 0; nt < 8; ++nt) {
        float s = sA[nt], qq = qA[nt];
        s += __shfl_xor(s, 16); qq += __shfl_xor(qq, 16);
        s += __shfl_xor(s, 32); qq += __shfl_xor(qq, 32);
        if (q == 0) {
            red[wid][nt * 16 + mh] = s;
            red[wid][128 + nt * 16 + mh] = qq;
        }
    }
    __syncthreads();
    atomicAdd(&stats[tid],
              red[0][tid] + red[1][tid] + red[2][tid] + red[3][tid]);
}

// ---- mlp2: full recompute path (fallback when workspace too small) ---------
__global__ __launch_bounds__(256, 2) void mlp2_kernel(
    const uint4* __restrict__ featbuf,
    const float* __restrict__ w0, const float* __restrict__ mom,
    const float* __restrict__ g0, const float* __restrict__ be0,
    const float* __restrict__ w1, const float* __restrict__ stats1,
    const float* __restrict__ g1, const float* __restrict__ be1,
    const float* __restrict__ w2,
    float* __restrict__ stats, float* __restrict__ gmax)
{
    __shared__ __align__(16) unsigned short sw0[64 * W0P];
    __shared__ __align__(16) unsigned short sw1[64 * WP];
    __shared__ __align__(16) unsigned short sw2[128 * WP];
    __shared__ __align__(16) unsigned short xb[4][32 * XP];
    __shared__ float sbn0[128];
    __shared__ float sbn1[128];
    __shared__ float red[4][256];
    const int tid = threadIdx.x, lane = tid & 63, wid = tid >> 6;

    for (int i = tid; i < 64 * W0P / 2; i += 256) ((unsigned*)sw0)[i] = 0;
    if (tid < 64) {
        compute_bn0(tid, mom, w0, g0, be0, sbn0);
    } else if (tid < 128) {
        const int ch = tid - 64;
        const float inv = 1.0f / (float)NROWS;
        const float mean = stats1[ch] * inv;
        const float var = stats1[64 + ch] * inv - mean * mean;
        const float scale = g1[ch] * rsqrtf(var + 1e-5f);
        sbn1[ch] = scale;
        sbn1[64 + ch] = be1[ch] - mean * scale;
    }
    __syncthreads();
    for (int i = tid; i < 192; i += 256) {
        const int o = i / 3, c = (i % 3) * 2;
        *(unsigned*)&sw0[o * W0P + c] = pack2bf(w0[o * 6 + c], w0[o * 6 + c + 1]);
    }
    for (int i = tid; i < 2048; i += 256) {
        const int o = i >> 5, k = (i & 31) * 2;
        *(unsigned*)&sw1[o * WP + k] = pack2bf(w1[o * 64 + k], w1[o * 64 + k + 1]);
    }
    for (int i = tid; i < 4096; i += 256) {
        const int o = i >> 5, k = (i & 31) * 2;
        *(unsigned*)&sw2[o * WP + k] = pack2bf(w2[o * 64 + k], w2[o * 64 + k + 1]);
    }

    const int mh = lane & 15, q = lane >> 4;
    unsigned short* X = xb[wid];
    const int rbase = blockIdx.x * 512 + wid * 32;
    float sA[8], qA[8];
#pragma unroll
    for (int i = 0; i < 8; ++i) { sA[i] = 0.f; qA[i] = 0.f; }

    for (int c = 0; c < 4; ++c) {
        __syncthreads();
        if (lane < 32) {
            const int r = rbase + c * 128 + lane;
            uint4* xq = (uint4*)&xb[wid][lane * XP];
            xq[0] = featbuf[r];
            xq[1] = make_uint4(0u, 0u, 0u, 0u);
            xq[2] = make_uint4(0u, 0u, 0u, 0u);
            xq[3] = make_uint4(0u, 0u, 0u, 0u);
        }
        __syncthreads();
        // L0
        f32x4 acc0[2][4] = {};
        {
            bf16x8 a[2], bw[4];
#pragma unroll
            for (int mt = 0; mt < 2; ++mt)
                a[mt] = *(const bf16x8*)&X[(mt * 16 + mh) * XP + q * 8];
#pragma unroll
            for (int nt = 0; nt < 4; ++nt)
                bw[nt] = *(const bf16x8*)&sw0[(nt * 16 + mh) * W0P + q * 8];
#pragma unroll
            for (int mt = 0; mt < 2; ++mt)
#pragma unroll
                for (int nt = 0; nt < 4; ++nt)
                    acc0[mt][nt] = __builtin_amdgcn_mfma_f32_16x16x32_bf16(
                        a[mt], bw[nt], acc0[mt][nt], 0, 0, 0);
        }
        __syncthreads();
#pragma unroll
        for (int nt = 0; nt < 4; ++nt) {
            const int ch = nt * 16 + mh;
            const float sc = sbn0[ch], sh = sbn0[64 + ch];
#pragma unroll
            for (int mt = 0; mt < 2; ++mt)
#pragma unroll
                for (int rr = 0; rr < 4; ++rr) {
                    const float v = fmaxf(fmaf(acc0[mt][nt][rr], sc, sh), 0.0f);
                    X[(mt * 16 + q * 4 + rr) * XP + ch] = f2bf(v);
                }
        }
        __syncthreads();
        // L1
        f32x4 acc1[2][4] = {};
#pragma unroll
        for (int ks = 0; ks < 2; ++ks) {
            bf16x8 a[2], bw[4];
#pragma unroll
            for (int mt = 0; mt < 2; ++mt)
                a[mt] = *(const bf16x8*)&X[(mt * 16 + mh) * XP + ks * 32 + q * 8];
#pragma unroll
            for (int nt = 0; nt < 4; ++nt)
                bw[nt] = *(const bf16x8*)&sw1[(nt * 16 + mh) * WP + ks * 32 + q * 8];
#pragma unroll
            for (int mt = 0; mt < 2; ++mt)
#pragma unroll
                for (int nt = 0; nt < 4; ++nt)
                    acc1[mt][nt] = __builtin_amdgcn_mfma_f32_16x16x32_bf16(
                        a[mt], bw[nt], acc1[mt][nt], 0, 0, 0);
        }
        __syncthreads();
#pragma unroll
        for (int nt = 0; nt < 4; ++nt) {
            const int ch = nt * 16 + mh;
            const float sc = sbn1[ch], sh = sbn1[64 + ch];
#pragma unroll
            for (int mt = 0; mt < 2; ++mt)
#pragma unroll
                for (int rr = 0; rr < 4; ++rr) {
                    const float v = fmaxf(fmaf(acc1[mt][nt][rr], sc, sh), 0.0f);
                    X[(mt * 16 + q * 4 + rr) * XP + ch] = f2bf(v);
                }
        }
        __syncthreads();
        // L2 + stats accumulate + per-group (32-row) max
        const int g = blockIdx.x * 16 + c * 4 + wid;
        bf16x8 a2[2][2];
#pragma unroll
        for (int mt = 0; mt < 2; ++mt)
#pragma unroll
            for (int ks = 0; ks < 2; ++ks)
                a2[mt][ks] = *(const bf16x8*)&X[(mt * 16 + mh) * XP + ks * 32 + q * 8];
#pragma unroll
        for (int nt = 0; nt < 8; ++nt) {
            f32x4 acc[2] = {};
#pragma unroll
            for (int ks = 0; ks < 2; ++ks) {
                const bf16x8 bw = *(const bf16x8*)&sw2[(nt * 16 + mh) * WP + ks * 32 + q * 8];
#pragma unroll
                for (int mt = 0; mt < 2; ++mt)
                    acc[mt] = __builtin_amdgcn_mfma_f32_16x16x32_bf16(
                        a2[mt][ks], bw, acc[mt], 0, 0, 0);
            }
            float m = -3.0e38f;
#pragma unroll
            for (int mt = 0; mt < 2; ++mt)
#pragma unroll
                for (int rr = 0; rr < 4; ++rr) {
                    const float v = acc[mt][rr];
                    sA[nt] += v;
                    qA[nt] = fmaf(v, v, qA[nt]);
                    m = fmaxf(m, v);
                }
            m = fmaxf(m, __shfl_xor(m, 16));
            m = fmaxf(m, __shfl_xor(m, 32));
            if (q == 0) gmax[(nt * 16 + mh) * 8192 + g] = m;
        }
    }
#pragma unroll
    for (int nt = 0; nt < 8; ++nt) {
        float s = sA[nt], qq = qA[nt];
        s += __shfl_xor(s, 16); qq += __shfl_xor(qq, 16);
        s += __shfl_xor(s, 32); qq += __shfl_xor(qq, 32);
        if (q == 0) {
            red[wid][nt * 16 + mh] = s;
            red[wid][128 + nt * 16 + mh] = qq;
        }
    }
    __syncthreads();
    atomicAdd(&stats[tid],
              red[0][tid] + red[1][tid] + red[2][tid] + red[3][tid]);
}

// ---------------------------------------------------------------------------
// final: bn2 computed inline from stats2; out2[b,o,s] = relu(bn2(gmax))
// ---------------------------------------------------------------------------
__global__ __launch_bounds__(256) void final_kernel(const float* __restrict__ gmax,
                                                    const float* __restrict__ stats2,
                                                    const float* __restrict__ g2,
                                                    const float* __restrict__ be2,
                                                    float* __restrict__ out2)
{
    __shared__ float sbn[256];
    const int tid = threadIdx.x;
    if (tid < 128) {
        const float inv = 1.0f / (float)NROWS;
        const float mean = stats2[tid] * inv;
        const float var = stats2[128 + tid] * inv - mean * mean;
        const float scale = g2[tid] * rsqrtf(var + 1e-5f);
        sbn[tid] = scale;
        sbn[128 + tid] = be2[tid] - mean * scale;
    }
    __syncthreads();
    const int t = blockIdx.x * 256 + tid;
    const int s = t & 1023;
    const int o = (t >> 10) & 127;
    const int b = t >> 17;
    const int g = (b << 10) | s;
    float v = gmax[o * 8192 + g];
    v = fmaf(v, sbn[o], sbn[128 + o]);
    out2[t] = fmaxf(v, 0.0f);
}

// ---------------------------------------------------------------------------
extern "C" void kernel_launch(void* const* d_in, const int* in_sizes, int n_in,
                              void* d_out, int out_size, void* d_ws, size_t ws_size,
                              hipStream_t stream)
{
    const float* xyz = (const float*)d_in[0];
    const float* pts = (const float*)d_in[1];
    const float* w0  = (const float*)d_in[2];
    const float* g0  = (const float*)d_in[4];
    const float* be0 = (const float*)d_in[5];
    const float* w1  = (const float*)d_in[6];
    const float* g1  = (const float*)d_in[8];
    const float* be1 = (const float*)d_in[9];
    const float* w2  = (const float*)d_in[10];
    const float* g2  = (const float*)d_in[12];
    const float* be2 = (const float*)d_in[13];

    float* out_xyz = (float*)d_out;             // (B,3,1024)
    float* out2    = out_xyz + 8 * 3 * NPOINT;  // (B,128,1024)

    char* wsb = (char*)d_ws;
    float* stats   = (float*)(wsb + 32768 + 1048576);   // 512 floats
    float* gmax    = stats + 1024;                      // 128*8192 floats (4 MB)
    uint4* featbuf = (uint4*)(gmax + 128 * 8192);       // 262144 uint4 (4 MB)
    uint4* l1buf   = featbuf + NROWS;                   // 8192*256 uint4 (32 MB)

    float* mom    = stats;                              // 42 floats
    float* stats1 = stats + 128;
    float* stats2 = stats + 256;

    // end of l1buf = 32768 + 1MB + 4KB + 4MB + 4MB + 32MB ≈ 43.03 MB
    const bool bigws = ws_size >= (size_t)43100000;

    hipMemsetAsync(stats, 0, 512 * sizeof(float), stream);

    fps_kernel<<<8, 256, 0, stream>>>(xyz, out_xyz);
    ball_kernel<<<2048, 256, 0, stream>>>(xyz, pts, out_xyz, mom, featbuf);
    if (bigws) {
        mlp1_kernel<<<512, 256, 0, stream>>>(featbuf, w0, mom, g0, be0,
                                             w1, stats1, l1buf);
        mlp2b_kernel<<<512, 256, 0, stream>>>(l1buf, stats1, g1, be1,
                                              w2, stats2, gmax);
    } else {
        mlp1_kernel<<<512, 256, 0, stream>>>(featbuf, w0, mom, g0, be0,
                                             w1, stats1, nullptr);
        mlp2_kernel<<<512, 256, 0, stream>>>(featbuf, w0, mom, g0, be0,
                                             w1, stats1, g1, be1,
                                             w2, stats2, gmax);
    }
    final_kernel<<<4096, 256, 0, stream>>>(gmax, stats2, g2, be2, out2);
}

// Round 5
// 773.403 us; speedup vs baseline: 1.3398x; 1.0011x over previous
//
#include <hip/hip_runtime.h>
#include <stdint.h>

#define NPTS   4096
#define NPOINT 1024
#define NSAMP  32
#define NROWS  262144   // B*NPOINT*NSAMP
#define RAD2   0.04f

typedef float v2f __attribute__((ext_vector_type(2)));
typedef __attribute__((ext_vector_type(8))) short bf16x8;
typedef __attribute__((ext_vector_type(4))) float f32x4;

// bf16 round-to-nearest-even
__device__ __forceinline__ unsigned short f2bf(float x) {
    unsigned u = __float_as_uint(x);
    return (unsigned short)((u + 0x7FFFu + ((u >> 16) & 1u)) >> 16);
}
__device__ __forceinline__ unsigned pack2bf(float a, float b) {
    return (unsigned)f2bf(a) | ((unsigned)f2bf(b) << 16);
}

// fused-DPP max helper (single-use feed -> v_max_f32_dpp)
#define DPPMAX(v, C)                                                           \
    fmaxf(__int_as_float(__builtin_amdgcn_update_dpp(                          \
              0, __float_as_int(v), C, 0xf, 0xf, true)),                       \
          (v))
// fused-DPP add helper (row_shr tree sum; bound_ctrl 0-fill = identity)
#define DPPADD(v, C)                                                           \
    (__int_as_float(__builtin_amdgcn_update_dpp(                               \
         0, __float_as_int(v), C, 0xf, 0xf, true)) +                           \
     (v))

// ---------------------------------------------------------------------------
// FPS: R14 structure (frozen: 8 variants all >=586). R19 adds ONE additive
// tweak: post-barrier speculative read of the wave's OWN candidate coords,
// issued in parallel with the wkey reads (independent loads). Winning wave
// (P=1/4) skips the dependent pxyz[farthest] round trip (~120cy). Placing
// the read pre-barrier would LOSE (compiler drains lgkmcnt(0) at s_barrier).
// Coordinates are identical values -> selection bit-identical.
// ---------------------------------------------------------------------------
__global__ __launch_bounds__(256) void fps_kernel(const float* __restrict__ xyz,
                                                  float* __restrict__ outx)
{
    __shared__ __align__(16) float4 pxyz[NPTS];
    __shared__ __align__(16) float4 orec[NPOINT];
    __shared__ __align__(16) unsigned long long wkey[2][4];
    const int b = blockIdx.x, tid = threadIdx.x;
    const int lane = tid & 63, wid = tid >> 6;
    const float* base = xyz + b * 3 * NPTS;

    float Xs[16], Ys[16], Zs[16];
#pragma unroll
    for (int j = 0; j < 16; ++j) {
        const int n = j * 256 + tid;
        Xs[j] = base[n];
        Ys[j] = base[NPTS + n];
        Zs[j] = base[2 * NPTS + n];
        pxyz[n] = make_float4(Xs[j], Ys[j], Zs[j], 0.0f);
    }
    v2f X2[8], Y2[8], Z2[8], D2[8];
#pragma unroll
    for (int j = 0; j < 8; ++j) {
        X2[j] = (v2f){Xs[2 * j], Xs[2 * j + 1]};
        Y2[j] = (v2f){Ys[2 * j], Ys[2 * j + 1]};
        Z2[j] = (v2f){Zs[2 * j], Zs[2 * j + 1]};
        D2[j] = (v2f){1e10f, 1e10f};
    }
    __syncthreads();
    float4 c4 = pxyz[0];
    float cx = c4.x, cy = c4.y, cz = c4.z;

    for (int t = 0; t < NPOINT; ++t) {
        if (tid == 0) orec[t] = make_float4(cx, cy, cz, 0.0f);
        const v2f cxv = (v2f){cx, cx}, cyv = (v2f){cy, cy}, czv = (v2f){cz, cz};
        float bv = -1.0f; int bi = 0;
#pragma unroll
        for (int j = 0; j < 8; ++j) {
            v2f nd;
            {
#pragma clang fp contract(off)
                const v2f dx = X2[j] - cxv;
                const v2f dy = Y2[j] - cyv;
                const v2f dz = Z2[j] - czv;
                const v2f m0 = dx * dx;
                const v2f m1 = dy * dy;
                const v2f m2 = dz * dz;
                const v2f d = (m0 + m1) + m2;
                nd = __builtin_elementwise_min(D2[j], d);
            }
            D2[j] = nd;
            // ascending indices + strict > keep the first occurrence
            if (nd.x > bv) { bv = nd.x; bi = j * 512 + tid; }
            if (nd.y > bv) { bv = nd.y; bi = j * 512 + 256 + tid; }
        }
        // value-first fused-DPP max
        float rv = bv;                       // bv >= 0 (bound_ctrl 0-fill safe)
        rv = DPPMAX(rv, 0x111);              // row_shr:1
        rv = DPPMAX(rv, 0x112);              // row_shr:2
        rv = DPPMAX(rv, 0x114);              // row_shr:4
        rv = DPPMAX(rv, 0x118);              // row_shr:8
        rv = DPPMAX(rv, 0x142);              // row_bcast:15
        rv = DPPMAX(rv, 0x143);              // row_bcast:31
        const unsigned wmax =
            (unsigned)__builtin_amdgcn_readlane(__float_as_int(rv), 63);
        // index resolution: ballot + scalar min over matching lanes
        unsigned long long mask = __ballot(__float_as_uint(bv) == wmax);
        unsigned best =
            (unsigned)__builtin_amdgcn_readlane(bi, (int)__builtin_ctzll(mask));
        mask &= mask - 1ull;
        while (mask) {
            const unsigned cand = (unsigned)__builtin_amdgcn_readlane(
                bi, (int)__builtin_ctzll(mask));
            best = cand < best ? cand : best;
            mask &= mask - 1ull;
        }
        if (lane == 0)
            wkey[t & 1][wid] = ((unsigned long long)wmax << 32) |
                               (unsigned)(~best);
        __syncthreads();
        // own-candidate speculative read, issued alongside the key reads
        float4 cand = pxyz[best];
        const ulonglong2* wk = (const ulonglong2*)wkey[t & 1];
        const ulonglong2 ka = wk[0], kb = wk[1];
        unsigned long long kk = ka.x;
        if (ka.y > kk) kk = ka.y;
        if (kb.x > kk) kk = kb.x;
        if (kb.y > kk) kk = kb.y;
        const int farthest = (int)(~(unsigned)kk) & (NPTS - 1);
        if (farthest != (int)best)           // wave-uniform branch
            cand = pxyz[farthest];
        cx = cand.x; cy = cand.y; cz = cand.z;
    }
    __syncthreads();
    float* ox = outx + b * 3 * NPOINT;
    for (int i = tid; i < NPOINT; i += 256) {
        const float4 c = orec[i];
        ox[i]              = c.x;
        ox[NPOINT + i]     = c.y;
        ox[2 * NPOINT + i] = c.z;
    }
}

// ---------------------------------------------------------------------------
// Ball query + fused moments + packed-bf16 feature store. One wave per query.
// R18 structure (prefetch + DPP moment reduce) kept frozen.
// ---------------------------------------------------------------------------
__global__ __launch_bounds__(256) void ball_kernel(const float* __restrict__ xyz,
                                                   const float* __restrict__ pts,
                                                   const float* __restrict__ outx,
                                                   float* __restrict__ mom,
                                                   uint4* __restrict__ featbuf)
{
    __shared__ float red[4][42];
    __shared__ int smyidx[4][NSAMP];
    const int tid = threadIdx.x;
    const int w = blockIdx.x * 4 + (tid >> 6);
    const int lane = tid & 63, wid = tid >> 6;
    const int b = w >> 10, s = w & 1023;
    const float* base = xyz + b * 3 * NPTS;
    const float cx = outx[b * 3 * NPOINT + s];
    const float cy = outx[b * 3 * NPOINT + NPOINT + s];
    const float cz = outx[b * 3 * NPOINT + 2 * NPOINT + s];
    const float sumS = __fadd_rn(__fadd_rn(__fmul_rn(cx, cx), __fmul_rn(cy, cy)),
                                 __fmul_rn(cz, cz));
    int cnt = 0, first_n = -1;
    int* myidx = smyidx[wid];

    // prefetch chunk 0
    float nx = base[lane], ny = base[NPTS + lane], nz = base[2 * NPTS + lane];
    for (int chunk = 0; chunk < NPTS / 64 && cnt < NSAMP; ++chunk) {
        const float x = nx, y = ny, z = nz;
        if (chunk + 1 < NPTS / 64) {
            const int nn = (chunk + 1) * 64 + lane;
            nx = base[nn]; ny = base[NPTS + nn]; nz = base[2 * NPTS + nn];
        }
        const int n = chunk * 64 + lane;
        float sumN = __fadd_rn(__fadd_rn(__fmul_rn(x, x), __fmul_rn(y, y)),
                               __fmul_rn(z, z));
        float dot = __fadd_rn(__fadd_rn(__fmul_rn(cx, x), __fmul_rn(cy, y)),
                              __fmul_rn(cz, z));
        float sq = __fsub_rn(__fadd_rn(sumS, sumN), __fmul_rn(2.0f, dot));
        bool keep = (sq <= RAD2);
        unsigned long long mask = __ballot(keep);
        if (first_n < 0 && mask) first_n = chunk * 64 + (int)__builtin_ctzll(mask);
        int pos = cnt + __popcll(mask & ((1ull << lane) - 1ull));
        if (keep && pos < NSAMP) myidx[pos] = n;
        cnt += __popcll(mask);
    }
    if (cnt < NSAMP) {
        if (lane >= cnt && lane < NSAMP) myidx[lane] = first_n;
    }

    // ---- fused moments + feature store for this wave's 32 rows ----
    float m[42];
#pragma unroll
    for (int i = 0; i < 42; ++i) m[i] = 0.f;
    if (lane < 32) {
        const int idx = myidx[lane];
        const float* pb = pts + b * 3 * NPTS;
        float f[6];
        f[0] = base[idx] - cx;
        f[1] = base[NPTS + idx] - cy;
        f[2] = base[2 * NPTS + idx] - cz;
        f[3] = pb[idx];
        f[4] = pb[NPTS + idx];
        f[5] = pb[2 * NPTS + idx];
        featbuf[w * NSAMP + lane] =
            make_uint4(pack2bf(f[0], f[1]), pack2bf(f[2], f[3]),
                       pack2bf(f[4], f[5]), 0u);
#pragma unroll
        for (int c = 0; c < 6; ++c) m[c] = f[c];
#pragma unroll
        for (int c = 0; c < 6; ++c)
#pragma unroll
            for (int d = 0; d < 6; ++d)
                m[6 + c * 6 + d] = f[c] * f[d];
    }
    // row_shr DPP tree: lane0/lane16 hold row-of-16 sums; one xor-16 shuffle
    // folds lanes 16-31 into lane 0 (lanes 32-63 are zero, ignored).
#pragma unroll
    for (int i = 0; i < 42; ++i) {
        float v = m[i];
        v = DPPADD(v, 0x111);   // row_shr:1
        v = DPPADD(v, 0x112);   // row_shr:2
        v = DPPADD(v, 0x114);   // row_shr:4
        v = DPPADD(v, 0x118);   // row_shr:8
        v += __shfl_xor(v, 16);
        m[i] = v;
    }
    if (lane == 0) {
#pragma unroll
        for (int i = 0; i < 42; ++i) red[wid][i] = m[i];
    }
    __syncthreads();
    if (tid < 42)
        atomicAdd(&mom[tid], red[0][tid] + red[1][tid] + red[2][tid] + red[3][tid]);
}

// bn0 from feature moments (biases cancel through BN shift; bilinear in W0)
__device__ __forceinline__ void compute_bn0(int o, const float* __restrict__ mom,
                                            const float* __restrict__ w0,
                                            const float* __restrict__ g,
                                            const float* __restrict__ be,
                                            float* __restrict__ sbn0)
{
    float w[6];
#pragma unroll
    for (int c = 0; c < 6; ++c) w[c] = w0[o * 6 + c];
    const float inv = 1.0f / (float)NROWS;
    float mean = 0.f;
#pragma unroll
    for (int c = 0; c < 6; ++c) mean = fmaf(w[c], mom[c], mean);
    mean *= inv;
    float ey2 = 0.f;
#pragma unroll
    for (int c = 0; c < 6; ++c) {
        float t = 0.f;
#pragma unroll
        for (int d = 0; d < 6; ++d) t = fmaf(w[d], mom[6 + c * 6 + d], t);
        ey2 = fmaf(w[c], t, ey2);
    }
    ey2 *= inv;
    const float var = ey2 - mean * mean;
    const float scale = g[o] * rsqrtf(var + 1e-5f);
    sbn0[o] = scale;
    sbn0[64 + o] = be[o] - mean * scale;
}

// ===========================================================================
// MFMA MLP kernels: 512 blocks x 512 rows (4 chunks of 128), weights staged
// once per block, stats in registers across chunks. Barrier-free chunk loop
// (xb[wid] wave-private; same-wave DS-pipe ordering).
// R19: chunk-0 featbuf prefetch hoisted to kernel top (hides HBM latency
// under weight staging).
// ===========================================================================
#define XP  72
#define WP  72
#define W0P 40

// ---- mlp1: feat -> L0 -> bn0(inline from moments) -> L1 -> stats1 [+store] --
__global__ __launch_bounds__(256, 2) void mlp1_kernel(
    const uint4* __restrict__ featbuf,
    const float* __restrict__ w0, const float* __restrict__ mom,
    const float* __restrict__ g0, const float* __restrict__ be0,
    const float* __restrict__ w1, float* __restrict__ stats,
    uint4* __restrict__ l1store)
{
    __shared__ __align__(16) unsigned short sw0[64 * W0P];
    __shared__ __align__(16) unsigned short sw1[64 * WP];
    __shared__ __align__(16) unsigned short xb[4][32 * XP];
    __shared__ float sbn0[128];
    __shared__ float red[4][128];
    const int tid = threadIdx.x, lane = tid & 63, wid = tid >> 6;
    const int rbase = blockIdx.x * 512 + wid * 32;

    // prefetch chunk 0 FIRST (independent of all LDS staging)
    uint4 preg = make_uint4(0u, 0u, 0u, 0u);
    if (lane < 32) preg = featbuf[rbase + lane];

    for (int i = tid; i < 64 * W0P / 2; i += 256) ((unsigned*)sw0)[i] = 0;
    if (tid < 64) compute_bn0(tid, mom, w0, g0, be0, sbn0);
    __syncthreads();
    for (int i = tid; i < 192; i += 256) {
        const int o = i / 3, c = (i % 3) * 2;
        *(unsigned*)&sw0[o * W0P + c] = pack2bf(w0[o * 6 + c], w0[o * 6 + c + 1]);
    }
    for (int i = tid; i < 2048; i += 256) {
        const int o = i >> 5, k = (i & 31) * 2;
        *(unsigned*)&sw1[o * WP + k] = pack2bf(w1[o * 64 + k], w1[o * 64 + k + 1]);
    }
    __syncthreads();   // weights + sbn0 visible to all waves

    const int mh = lane & 15, q = lane >> 4;
    unsigned short* X = xb[wid];
    float sA[4] = {0.f, 0.f, 0.f, 0.f}, qA[4] = {0.f, 0.f, 0.f, 0.f};

    for (int c = 0; c < 4; ++c) {
        if (lane < 32) {
            uint4* xq = (uint4*)&xb[wid][lane * XP];
            xq[0] = preg;
            xq[1] = make_uint4(0u, 0u, 0u, 0u);
            xq[2] = make_uint4(0u, 0u, 0u, 0u);
            xq[3] = make_uint4(0u, 0u, 0u, 0u);
            if (c < 3) preg = featbuf[rbase + (c + 1) * 128 + lane];
        }
        // L0 (same-wave LDS: DS pipe in-order; compiler inserts lgkmcnt)
        f32x4 acc0[2][4] = {};
        {
            bf16x8 a[2], bw[4];
#pragma unroll
            for (int mt = 0; mt < 2; ++mt)
                a[mt] = *(const bf16x8*)&X[(mt * 16 + mh) * XP + q * 8];
#pragma unroll
            for (int nt = 0; nt < 4; ++nt)
                bw[nt] = *(const bf16x8*)&sw0[(nt * 16 + mh) * W0P + q * 8];
#pragma unroll
            for (int mt = 0; mt < 2; ++mt)
#pragma unroll
                for (int nt = 0; nt < 4; ++nt)
                    acc0[mt][nt] = __builtin_amdgcn_mfma_f32_16x16x32_bf16(
                        a[mt], bw[nt], acc0[mt][nt], 0, 0, 0);
        }
#pragma unroll
        for (int nt = 0; nt < 4; ++nt) {
            const int ch = nt * 16 + mh;
            const float sc = sbn0[ch], sh = sbn0[64 + ch];
#pragma unroll
            for (int mt = 0; mt < 2; ++mt)
#pragma unroll
                for (int rr = 0; rr < 4; ++rr) {
                    const float v = fmaxf(fmaf(acc0[mt][nt][rr], sc, sh), 0.0f);
                    X[(mt * 16 + q * 4 + rr) * XP + ch] = f2bf(v);
                }
        }
        // L1
        f32x4 acc1[2][4] = {};
#pragma unroll
        for (int ks = 0; ks < 2; ++ks) {
            bf16x8 a[2], bw[4];
#pragma unroll
            for (int mt = 0; mt < 2; ++mt)
                a[mt] = *(const bf16x8*)&X[(mt * 16 + mh) * XP + ks * 32 + q * 8];
#pragma unroll
            for (int nt = 0; nt < 4; ++nt)
                bw[nt] = *(const bf16x8*)&sw1[(nt * 16 + mh) * WP + ks * 32 + q * 8];
#pragma unroll
            for (int mt = 0; mt < 2; ++mt)
#pragma unroll
                for (int nt = 0; nt < 4; ++nt)
                    acc1[mt][nt] = __builtin_amdgcn_mfma_f32_16x16x32_bf16(
                        a[mt], bw[nt], acc1[mt][nt], 0, 0, 0);
        }
        // stats from f32 acc1 (bit-identical to recompute path)
#pragma unroll
        for (int nt = 0; nt < 4; ++nt)
#pragma unroll
            for (int mt = 0; mt < 2; ++mt)
#pragma unroll
                for (int rr = 0; rr < 4; ++rr) {
                    const float v = acc1[mt][nt][rr];
                    sA[nt] += v;
                    qA[nt] = fmaf(v, v, qA[nt]);
                }
        if (l1store) {
            // stage bf16(L1out pre-BN) in the wave-private X region
#pragma unroll
            for (int nt = 0; nt < 4; ++nt) {
                const int ch = nt * 16 + mh;
#pragma unroll
                for (int mt = 0; mt < 2; ++mt)
#pragma unroll
                    for (int rr = 0; rr < 4; ++rr)
                        X[(mt * 16 + q * 4 + rr) * XP + ch] =
                            f2bf(acc1[mt][nt][rr]);
            }
            // wave-private: same-wave LDS write->read ordering via DS pipe
            uint4* dst = l1store +
                         (size_t)(blockIdx.x * 16 + c * 4 + wid) * 256;
#pragma unroll
            for (int k = 0; k < 4; ++k) {
                const int idx = lane * 4 + k;
                const int row = idx >> 3, c8 = (idx & 7) * 8;
                dst[idx] = *(const uint4*)&X[row * XP + c8];
            }
        }
    }
#pragma unroll
    for (int nt = 0; nt < 4; ++nt) {
        float s = sA[nt], qq = qA[nt];
        s += __shfl_xor(s, 16); qq += __shfl_xor(qq, 16);
        s += __shfl_xor(s, 32); qq += __shfl_xor(qq, 32);
        if (q == 0) {
            red[wid][nt * 16 + mh] = s;
            red[wid][64 + nt * 16 + mh] = qq;
        }
    }
    __syncthreads();
    if (tid < 128)
        atomicAdd(&stats[tid],
                  red[0][tid] + red[1][tid] + red[2][tid] + red[3][tid]);
}

// ---- mlp2b: l1buf -> bn1(in-register) -> L2 -> stats2 + max (lean path) ----
// R19: raw l1buf loads double-buffered in registers (chunk-0 loads hoisted
// above the staging barrier; chunk c+1 issued before the MFMA loop).
__global__ __launch_bounds__(256, 2) void mlp2b_kernel(
    const uint4* __restrict__ l1buf,
    const float* __restrict__ stats1,
    const float* __restrict__ g1, const float* __restrict__ be1,
    const float* __restrict__ w2,
    float* __restrict__ stats, float* __restrict__ gmax)
{
    __shared__ __align__(16) unsigned short sw2[128 * WP];
    __shared__ float sbn1[128];
    __shared__ float red[4][256];
    const int tid = threadIdx.x, lane = tid & 63, wid = tid >> 6;
    const int mh = lane & 15, q = lane >> 4;

    // prefetch chunk 0 raw (independent of LDS staging)
    uint4 praw00, praw01, praw10, praw11;
    {
        const uint4* s0 = l1buf + (size_t)(blockIdx.x * 16 + wid) * 256;
        praw00 = s0[mh * 8 + q];
        praw01 = s0[mh * 8 + 4 + q];
        praw10 = s0[(16 + mh) * 8 + q];
        praw11 = s0[(16 + mh) * 8 + 4 + q];
    }

    if (tid < 64) {
        const float inv = 1.0f / (float)NROWS;
        const float mean = stats1[tid] * inv;
        const float var = stats1[64 + tid] * inv - mean * mean;
        const float scale = g1[tid] * rsqrtf(var + 1e-5f);
        sbn1[tid] = scale;
        sbn1[64 + tid] = be1[tid] - mean * scale;
    }
    for (int i = tid; i < 4096; i += 256) {
        const int o = i >> 5, k = (i & 31) * 2;
        *(unsigned*)&sw2[o * WP + k] = pack2bf(w2[o * 64 + k], w2[o * 64 + k + 1]);
    }
    __syncthreads();

    // per-lane bn1 coefficients: channels ks*32 + q*8 + j (lane-invariant)
    float sc[2][8], sh[2][8];
#pragma unroll
    for (int ks = 0; ks < 2; ++ks)
#pragma unroll
        for (int j = 0; j < 8; ++j) {
            const int ch = ks * 32 + q * 8 + j;
            sc[ks][j] = sbn1[ch];
            sh[ks][j] = sbn1[64 + ch];
        }

    float sA[8], qA[8];
#pragma unroll
    for (int i = 0; i < 8; ++i) { sA[i] = 0.f; qA[i] = 0.f; }

    for (int c = 0; c < 4; ++c) {
        const int g = blockIdx.x * 16 + c * 4 + wid;
        // build a2 from the prefetched raw values
        bf16x8 a2[2][2];
#pragma unroll
        for (int mt = 0; mt < 2; ++mt)
#pragma unroll
            for (int ks = 0; ks < 2; ++ks) {
                const uint4 v = (mt == 0) ? (ks == 0 ? praw00 : praw01)
                                          : (ks == 0 ? praw10 : praw11);
                const unsigned* pv = (const unsigned*)&v;
                unsigned r[4];
#pragma unroll
                for (int p = 0; p < 4; ++p) {
                    const unsigned u = pv[p];
                    const float f0 = __uint_as_float(u << 16);
                    const float f1 = __uint_as_float(u & 0xFFFF0000u);
                    const float v0 =
                        fmaxf(fmaf(f0, sc[ks][2 * p], sh[ks][2 * p]), 0.0f);
                    const float v1 =
                        fmaxf(fmaf(f1, sc[ks][2 * p + 1], sh[ks][2 * p + 1]),
                              0.0f);
                    r[p] = pack2bf(v0, v1);
                }
                const uint4 packed = make_uint4(r[0], r[1], r[2], r[3]);
                a2[mt][ks] = __builtin_bit_cast(bf16x8, packed);
            }
        // prefetch chunk c+1 raw (overlaps with the MFMA loop below)
        if (c < 3) {
            const uint4* sn =
                l1buf + (size_t)(blockIdx.x * 16 + (c + 1) * 4 + wid) * 256;
            praw00 = sn[mh * 8 + q];
            praw01 = sn[mh * 8 + 4 + q];
            praw10 = sn[(16 + mh) * 8 + q];
            praw11 = sn[(16 + mh) * 8 + 4 + q];
        }
        // L2 + stats accumulate + per-group (32-row) max
#pragma unroll
        for (int nt = 0; nt < 8; ++nt) {
            f32x4 acc[2] = {};
#pragma unroll
            for (int ks = 0; ks < 2; ++ks) {
                const bf16x8 bw =
                    *(const bf16x8*)&sw2[(nt * 16 + mh) * WP + ks * 32 + q * 8];
#pragma unroll
                for (int mt = 0; mt < 2; ++mt)
                    acc[mt] = __builtin_amdgcn_mfma_f32_16x16x32_bf16(
                        a2[mt][ks], bw, acc[mt], 0, 0, 0);
            }
            float m = -3.0e38f;
#pragma unroll
            for (int mt = 0; mt < 2; ++mt)
#pragma unroll
                for (int rr = 0; rr < 4; ++rr) {
                    const float v = acc[mt][rr];
                    sA[nt] += v;
                    qA[nt] = fmaf(v, v, qA[nt]);
                    m = fmaxf(m, v);
                }
            m = fmaxf(m, __shfl_xor(m, 16));
            m = fmaxf(m, __shfl_xor(m, 32));
            if (q == 0) gmax[(nt * 16 + mh) * 8192 + g] = m;
        }
    }
#pragma unroll
    for (int nt = 0; nt < 8; ++nt) {
        float s = sA[nt], qq = qA[nt];
        s += __shfl_xor(s, 16); qq += __shfl_xor(qq, 16);
        s += __shfl_xor(s, 32); qq += __shfl_xor(qq, 32);
        if (q == 0) {
            red[wid][nt * 16 + mh] = s;
            red[wid][128 + nt * 16 + mh] = qq;
        }
    }
    __syncthreads();
    atomicAdd(&stats[tid],
              red[0][tid] + red[1][tid] + red[2][tid] + red[3][tid]);
}

// ---- mlp2: full recompute path (fallback when workspace too small) ---------
__global__ __launch_bounds__(256, 2) void mlp2_kernel(
    const uint4* __restrict__ featbuf,
    const float* __restrict__ w0, const float* __restrict__ mom,
    const float* __restrict__ g0, const float* __restrict__ be0,
    const float* __restrict__ w1, const float* __restrict__ stats1,
    const float* __restrict__ g1, const float* __restrict__ be1,
    const float* __restrict__ w2,
    float* __restrict__ stats, float* __restrict__ gmax)
{
    __shared__ __align__(16) unsigned short sw0[64 * W0P];
    __shared__ __align__(16) unsigned short sw1[64 * WP];
    __shared__ __align__(16) unsigned short sw2[128 * WP];
    __shared__ __align__(16) unsigned short xb[4][32 * XP];
    __shared__ float sbn0[128];
    __shared__ float sbn1[128];
    __shared__ float red[4][256];
    const int tid = threadIdx.x, lane = tid & 63, wid = tid >> 6;

    for (int i = tid; i < 64 * W0P / 2; i += 256) ((unsigned*)sw0)[i] = 0;
    if (tid < 64) {
        compute_bn0(tid, mom, w0, g0, be0, sbn0);
    } else if (tid < 128) {
        const int ch = tid - 64;
        const float inv = 1.0f / (float)NROWS;
        const float mean = stats1[ch] * inv;
        const float var = stats1[64 + ch] * inv - mean * mean;
        const float scale = g1[ch] * rsqrtf(var + 1e-5f);
        sbn1[ch] = scale;
        sbn1[64 + ch] = be1[ch] - mean * scale;
    }
    __syncthreads();
    for (int i = tid; i < 192; i += 256) {
        const int o = i / 3, c = (i % 3) * 2;
        *(unsigned*)&sw0[o * W0P + c] = pack2bf(w0[o * 6 + c], w0[o * 6 + c + 1]);
    }
    for (int i = tid; i < 2048; i += 256) {
        const int o = i >> 5, k = (i & 31) * 2;
        *(unsigned*)&sw1[o * WP + k] = pack2bf(w1[o * 64 + k], w1[o * 64 + k + 1]);
    }
    for (int i = tid; i < 4096; i += 256) {
        const int o = i >> 5, k = (i & 31) * 2;
        *(unsigned*)&sw2[o * WP + k] = pack2bf(w2[o * 64 + k], w2[o * 64 + k + 1]);
    }

    const int mh = lane & 15, q = lane >> 4;
    unsigned short* X = xb[wid];
    const int rbase = blockIdx.x * 512 + wid * 32;
    float sA[8], qA[8];
#pragma unroll
    for (int i = 0; i < 8; ++i) { sA[i] = 0.f; qA[i] = 0.f; }

    for (int c = 0; c < 4; ++c) {
        __syncthreads();
        if (lane < 32) {
            const int r = rbase + c * 128 + lane;
            uint4* xq = (uint4*)&xb[wid][lane * XP];
            xq[0] = featbuf[r];
            xq[1] = make_uint4(0u, 0u, 0u, 0u);
            xq[2] = make_uint4(0u, 0u, 0u, 0u);
            xq[3] = make_uint4(0u, 0u, 0u, 0u);
        }
        __syncthreads();
        // L0
        f32x4 acc0[2][4] = {};
        {
            bf16x8 a[2], bw[4];
#pragma unroll
            for (int mt = 0; mt < 2; ++mt)
                a[mt] = *(const bf16x8*)&X[(mt * 16 + mh) * XP + q * 8];
#pragma unroll
            for (int nt = 0; nt < 4; ++nt)
                bw[nt] = *(const bf16x8*)&sw0[(nt * 16 + mh) * W0P + q * 8];
#pragma unroll
            for (int mt = 0; mt < 2; ++mt)
#pragma unroll
                for (int nt = 0; nt < 4; ++nt)
                    acc0[mt][nt] = __builtin_amdgcn_mfma_f32_16x16x32_bf16(
                        a[mt], bw[nt], acc0[mt][nt], 0, 0, 0);
        }
        __syncthreads();
#pragma unroll
        for (int nt = 0; nt < 4; ++nt) {
            const int ch = nt * 16 + mh;
            const float sc = sbn0[ch], sh = sbn0[64 + ch];
#pragma unroll
            for (int mt = 0; mt < 2; ++mt)
#pragma unroll
                for (int rr = 0; rr < 4; ++rr) {
                    const float v = fmaxf(fmaf(acc0[mt][nt][rr], sc, sh), 0.0f);
                    X[(mt * 16 + q * 4 + rr) * XP + ch] = f2bf(v);
                }
        }
        __syncthreads();
        // L1
        f32x4 acc1[2][4] = {};
#pragma unroll
        for (int ks = 0; ks < 2; ++ks) {
            bf16x8 a[2], bw[4];
#pragma unroll
            for (int mt = 0; mt < 2; ++mt)
                a[mt] = *(const bf16x8*)&X[(mt * 16 + mh) * XP + ks * 32 + q * 8];
#pragma unroll
            for (int nt = 0; nt < 4; ++nt)
                bw[nt] = *(const bf16x8*)&sw1[(nt * 16 + mh) * WP + ks * 32 + q * 8];
#pragma unroll
            for (int mt = 0; mt < 2; ++mt)
#pragma unroll
                for (int nt = 0; nt < 4; ++nt)
                    acc1[mt][nt] = __builtin_amdgcn_mfma_f32_16x16x32_bf16(
                        a[mt], bw[nt], acc1[mt][nt], 0, 0, 0);
        }
        __syncthreads();
#pragma unroll
        for (int nt = 0; nt < 4; ++nt) {
            const int ch = nt * 16 + mh;
            const float sc = sbn1[ch], sh = sbn1[64 + ch];
#pragma unroll
            for (int mt = 0; mt < 2; ++mt)
#pragma unroll
                for (int rr = 0; rr < 4; ++rr) {
                    const float v = fmaxf(fmaf(acc1[mt][nt][rr], sc, sh), 0.0f);
                    X[(mt * 16 + q * 4 + rr) * XP + ch] = f2bf(v);
                }
        }
        __syncthreads();
        // L2 + stats accumulate + per-group (32-row) max
        const int g = blockIdx.x * 16 + c * 4 + wid;
        bf16x8 a2[2][2];
#pragma unroll
        for (int mt = 0; mt < 2; ++mt)
#pragma unroll
            for (int ks = 0; ks < 2; ++ks)
                a2[mt][ks] = *(const bf16x8*)&X[(mt * 16 + mh) * XP + ks * 32 + q * 8];
#pragma unroll
        for (int nt = 0; nt < 8; ++nt) {
            f32x4 acc[2] = {};
#pragma unroll
            for (int ks = 0; ks < 2; ++ks) {
                const bf16x8 bw = *(const bf16x8*)&sw2[(nt * 16 + mh) * WP + ks * 32 + q * 8];
#pragma unroll
                for (int mt = 0; mt < 2; ++mt)
                    acc[mt] = __builtin_amdgcn_mfma_f32_16x16x32_bf16(
                        a2[mt][ks], bw, acc[mt], 0, 0, 0);
            }
            float m = -3.0e38f;
#pragma unroll
            for (int mt = 0; mt < 2; ++mt)
#pragma unroll
                for (int rr = 0; rr < 4; ++rr) {
                    const float v = acc[mt][rr];
                    sA[nt] += v;
                    qA[nt] = fmaf(v, v, qA[nt]);
                    m = fmaxf(m, v);
                }
            m = fmaxf(m, __shfl_xor(m, 16));
            m = fmaxf(m, __shfl_xor(m, 32));
            if (q == 0) gmax[(nt * 16 + mh) * 8192 + g] = m;
        }
    }
#pragma unroll
    for (int nt = 0; nt < 8; ++nt) {
        float s = sA[nt], qq = qA[nt];
        s += __shfl_xor(s, 16); qq += __shfl_xor(qq, 16);
        s += __shfl_xor(s, 32); qq += __shfl_xor(qq, 32);
        if (q == 0) {
            red[wid][nt * 16 + mh] = s;
            red[wid][128 + nt * 16 + mh] = qq;
        }
    }
    __syncthreads();
    atomicAdd(&stats[tid],
              red[0][tid] + red[1][tid] + red[2][tid] + red[3][tid]);
}

// ---------------------------------------------------------------------------
// final: bn2 inline from stats2; float4 per thread (R19), 1024 blocks.
// 4 consecutive s share (b,o) -> uniform sbn; gmax/out2 accessed as float4.
// ---------------------------------------------------------------------------
__global__ __launch_bounds__(256) void final_kernel(const float* __restrict__ gmax,
                                                    const float* __restrict__ stats2,
                                                    const float* __restrict__ g2,
                                                    const float* __restrict__ be2,
                                                    float* __restrict__ out2)
{
    __shared__ float sbn[256];
    const int tid = threadIdx.x;
    if (tid < 128) {
        const float inv = 1.0f / (float)NROWS;
        const float mean = stats2[tid] * inv;
        const float var = stats2[128 + tid] * inv - mean * mean;
        const float scale = g2[tid] * rsqrtf(var + 1e-5f);
        sbn[tid] = scale;
        sbn[128 + tid] = be2[tid] - mean * scale;
    }
    __syncthreads();
    const int t4 = (blockIdx.x * 256 + tid) * 4;
    const int s = t4 & 1023;                  // 4 consecutive s, same o/b
    const int o = (t4 >> 10) & 127;
    const int b = t4 >> 17;
    const int g = (b << 10) | s;
    const float4 v4 = *(const float4*)&gmax[o * 8192 + g];
    const float sc = sbn[o], sh = sbn[128 + o];
    float4 r;
    r.x = fmaxf(fmaf(v4.x, sc, sh), 0.0f);
    r.y = fmaxf(fmaf(v4.y, sc, sh), 0.0f);
    r.z = fmaxf(fmaf(v4.z, sc, sh), 0.0f);
    r.w = fmaxf(fmaf(v4.w, sc, sh), 0.0f);
    *(float4*)&out2[t4] = r;
}

// ---------------------------------------------------------------------------
extern "C" void kernel_launch(void* const* d_in, const int* in_sizes, int n_in,
                              void* d_out, int out_size, void* d_ws, size_t ws_size,
                              hipStream_t stream)
{
    const float* xyz = (const float*)d_in[0];
    const float* pts = (const float*)d_in[1];
    const float* w0  = (const float*)d_in[2];
    const float* g0  = (const float*)d_in[4];
    const float* be0 = (const float*)d_in[5];
    const float* w1  = (const float*)d_in[6];
    const float* g1  = (const float*)d_in[8];
    const float* be1 = (const float*)d_in[9];
    const float* w2  = (const float*)d_in[10];
    const float* g2  = (const float*)d_in[12];
    const float* be2 = (const float*)d_in[13];

    float* out_xyz = (float*)d_out;             // (B,3,1024)
    float* out2    = out_xyz + 8 * 3 * NPOINT;  // (B,128,1024)

    char* wsb = (char*)d_ws;
    float* stats   = (float*)(wsb + 32768 + 1048576);   // 512 floats
    float* gmax    = stats + 1024;                      // 128*8192 floats (4 MB)
    uint4* featbuf = (uint4*)(gmax + 128 * 8192);       // 262144 uint4 (4 MB)
    uint4* l1buf   = featbuf + NROWS;                   // 8192*256 uint4 (32 MB)

    float* mom    = stats;                              // 42 floats
    float* stats1 = stats + 128;
    float* stats2 = stats + 256;

    // end of l1buf = 32768 + 1MB + 4KB + 4MB + 4MB + 32MB ≈ 43.03 MB
    const bool bigws = ws_size >= (size_t)43100000;

    hipMemsetAsync(stats, 0, 512 * sizeof(float), stream);

    fps_kernel<<<8, 256, 0, stream>>>(xyz, out_xyz);
    ball_kernel<<<2048, 256, 0, stream>>>(xyz, pts, out_xyz, mom, featbuf);
    if (bigws) {
        mlp1_kernel<<<512, 256, 0, stream>>>(featbuf, w0, mom, g0, be0,
                                             w1, stats1, l1buf);
        mlp2b_kernel<<<512, 256, 0, stream>>>(l1buf, stats1, g1, be1,
                                              w2, stats2, gmax);
    } else {
        mlp1_kernel<<<512, 256, 0, stream>>>(featbuf, w0, mom, g0, be0,
                                             w1, stats1, nullptr);
        mlp2_kernel<<<512, 256, 0, stream>>>(featbuf, w0, mom, g0, be0,
                                             w1, stats1, g1, be1,
                                             w2, stats2, gmax);
    }
    final_kernel<<<1024, 256, 0, stream>>>(gmax, stats2, g2, be2, out2);
}